// Round 9
// baseline (576.835 us; speedup 1.0000x reference)
//
#include <hip/hip_runtime.h>
#include <hip/hip_fp16.h>
#include <cstddef>

#define TPB 256
#define SCHUNK 4096   // scan elements per block (256 thr x 16)
#define REPL 8        // histogram/cursor replication factor

// Replica mapping shared by hist & fill: block covers 2*TPB=512 edges,
// r = blockIdx & 7.  MUST be identical in both kernels (cursor capacity).

// ---------------------------------------------------------------------------
// Histogram (count only), replicated; 2 edges/thread.
// ---------------------------------------------------------------------------
__global__ void hist_kernel(const int* __restrict__ tgt, int* __restrict__ cntR,
                            int n, int E) {
    const int base = blockIdx.x * (2 * TPB) + threadIdx.x;
    const int r = blockIdx.x & (REPL - 1);
#pragma unroll
    for (int j = 0; j < 2; ++j) {
        int e = base + j * TPB;
        if (e < E) atomicAdd(&cntR[r * n + tgt[e]], 1);
    }
}

// ---------------------------------------------------------------------------
// Scan phase 1: per-chunk sums over m = 8n elements, key idx = t*8+r.
// ---------------------------------------------------------------------------
__global__ __launch_bounds__(256) void scan_reduce_kernel(
        const int* __restrict__ cntR, int* __restrict__ blocksum, int n, int m) {
    __shared__ int red[4];
    const int tid = threadIdx.x;
    const int base = blockIdx.x * SCHUNK;
    int s = 0;
    for (int i = tid; i < SCHUNK; i += 256) {
        int idx = base + i;
        if (idx < m) s += cntR[(idx & (REPL - 1)) * n + (idx >> 3)];
    }
#pragma unroll
    for (int off = 32; off; off >>= 1) s += __shfl_down(s, off, 64);
    if ((tid & 63) == 0) red[tid >> 6] = s;
    __syncthreads();
    if (tid == 0) blocksum[blockIdx.x] = red[0] + red[1] + red[2] + red[3];
}

// Scan phase 2: exclusive scan + global offset (parallel blocksum prefix).
__global__ __launch_bounds__(256) void scan_final_kernel(
        const int* __restrict__ cntR, const int* __restrict__ blocksum,
        int* __restrict__ rowstart8, int n, int m) {
    __shared__ int sm[256];
    __shared__ int red[4];
    __shared__ int goff_sm;
    const int tid = threadIdx.x;
    const int b = blockIdx.x;
    int v = (tid < b) ? blocksum[tid] : 0;
#pragma unroll
    for (int off = 32; off; off >>= 1) v += __shfl_down(v, off, 64);
    if ((tid & 63) == 0) red[tid >> 6] = v;
    __syncthreads();
    if (tid == 0) goff_sm = red[0] + red[1] + red[2] + red[3];
    __syncthreads();
    const int goff = goff_sm;

    const int start = b * SCHUNK + tid * 16;
    int items[16];
    int tsum = 0;
#pragma unroll
    for (int i = 0; i < 16; ++i) {
        int idx = start + i;
        int val = (idx < m) ? cntR[(idx & (REPL - 1)) * n + (idx >> 3)] : 0;
        items[i] = tsum;
        tsum += val;
    }
    sm[tid] = tsum;
    __syncthreads();
#pragma unroll
    for (int off = 1; off < 256; off <<= 1) {
        int add = (tid >= off) ? sm[tid - off] : 0;
        __syncthreads();
        sm[tid] += add;
        __syncthreads();
    }
    const int texcl = goff + sm[tid] - tsum;
#pragma unroll
    for (int i = 0; i < 16; ++i) {
        int idx = start + i;
        if (idx < m) rowstart8[idx] = texcl + items[i];
    }
    if (b == gridDim.x - 1 && tid == 255) rowstart8[m] = goff + sm[255];
}

// Copy rowstart8 -> cursor (coalesced), so fill needs no rowstart read.
__global__ void cursor_init_kernel(const int* __restrict__ rowstart8,
                                   int* __restrict__ cursor, int m) {
    int i = blockIdx.x * blockDim.x + threadIdx.x;
    if (i < m) cursor[i] = rowstart8[i];
}

// ---------------------------------------------------------------------------
// Fill CSR: edat[slot] = {(src<<8)|negflag, bitcast(raw w)}; slot straight
// from the pre-initialized cursor (atomic only). 2 edges/thread.
// ---------------------------------------------------------------------------
__global__ void fill_kernel(const int* __restrict__ src, const int* __restrict__ tgt,
                            const float* __restrict__ ew,
                            int* __restrict__ cursor, int2* __restrict__ edat,
                            int n, int E) {
    const int base = blockIdx.x * (2 * TPB) + threadIdx.x;
    const int r = blockIdx.x & (REPL - 1);
#pragma unroll
    for (int j = 0; j < 2; ++j) {
        int e = base + j * TPB;
        if (e < E) {
            int t = tgt[e], s = src[e];
            float w = ew[e];
            int pos = atomicAdd(&cursor[t * 8 + r], 1);
            int flag = (w < 0.0f) ? 1 : 0;
            edat[pos] = make_int2((s << 8) | flag, __float_as_int(w));
        }
    }
}

// ---------------------------------------------------------------------------
// Degrees + dinv + norm-fold: pass 1 sums |w| by sign; pass 2 rewrites
// edat.y = w * (flag ? dinvn[t] : dinvp[t])  (layer-independent norm).
// ---------------------------------------------------------------------------
__global__ void deg_dinv_kernel(const int* __restrict__ rowstart8,
                                int2* __restrict__ edat,
                                float* __restrict__ dinvp, float* __restrict__ dinvn, int n) {
    int t = blockIdx.x * blockDim.x + threadIdx.x;
    if (t >= n) return;
    int beg = rowstart8[8 * t], end = rowstart8[8 * t + 8];
    float p = 0.f, q = 0.f;
    for (int e = beg; e < end; ++e) {
        float w = __int_as_float(edat[e].y);
        p += fmaxf(w, 0.f);
        q += fmaxf(-w, 0.f);
    }
    float dp = rsqrtf(p + 1.0f), dn = rsqrtf(q + 1.0f);
    dinvp[t] = dp;
    dinvn[t] = dn;
    for (int e = beg; e < end; ++e) {
        int2 d = edat[e];
        float nv = __int_as_float(d.y) * ((d.x & 1) ? dn : dp);
        edat[e].y = __float_as_int(nv);
    }
}

// ---------------------------------------------------------------------------
// Staging load helpers (4 contiguous elems -> float4), fp32 or fp16 input.
// ---------------------------------------------------------------------------
__device__ inline float4 load4f(const float* p) { return *(const float4*)p; }
__device__ inline float4 load4f(const __half* p) {
    float2 a = __half22float2(*(const __half2*)p);
    float2 b = __half22float2(*(const __half2*)(p + 2));
    return make_float4(a.x, a.y, b.x, b.y);
}

// ---------------------------------------------------------------------------
// Tiled dual GEMM, fp32 compute, FP16 OUTPUT with dinv-scaled epilogue:
// hp' = half((X@Wp^T)*dinvp[row]).  TIN = float (layer1) or __half (layer2).
// ---------------------------------------------------------------------------
template<typename TIN, int IN, int OUTF, bool DUAL>
__global__ __launch_bounds__(256) void gemm_tiled(
        const TIN* __restrict__ x,
        const float* __restrict__ Wp, const float* __restrict__ Wn,
        const float* __restrict__ dinvp, const float* __restrict__ dinvn,
        __half* __restrict__ hp, __half* __restrict__ hn, int n) {
    constexpr int BM = 64, BN = 128, BK = 32;
    __shared__ float xT[BK][BM + 4];
    __shared__ float Ws[BK][BN + 4];

    const int tid = threadIdx.x;
    const int rowbase = blockIdx.x * BM;
    const float* __restrict__ Wsel = DUAL ? nullptr : (blockIdx.y ? Wn : Wp);

    const int r0 = (tid & 15) * 4;
    const int c0 = (tid >> 4) * 8;

    float acc[4][8];
#pragma unroll
    for (int i = 0; i < 4; ++i)
#pragma unroll
        for (int j = 0; j < 8; ++j) acc[i][j] = 0.f;

    for (int k0 = 0; k0 < IN; k0 += BK) {
#pragma unroll
        for (int i = 0; i < (BM * BK) / (4 * TPB); ++i) {
            int lin = tid + i * TPB;
            int row = lin >> 3;
            int kq  = lin & 7;
            int grow = rowbase + row;
            if (grow > n - 1) grow = n - 1;
            float4 v = load4f(x + (size_t)grow * IN + k0 + kq * 4);
            int kk = kq * 4;
            xT[kk + 0][row] = v.x; xT[kk + 1][row] = v.y;
            xT[kk + 2][row] = v.z; xT[kk + 3][row] = v.w;
        }
#pragma unroll
        for (int i = 0; i < (BN * BK) / (4 * TPB); ++i) {
            int lin = tid + i * TPB;
            int c  = lin >> 3;
            int kq = lin & 7;
            const float* wrow;
            if (DUAL) wrow = (c < OUTF) ? (Wp + (size_t)c * IN) : (Wn + (size_t)(c - OUTF) * IN);
            else      wrow = Wsel + (size_t)c * IN;
            float4 v = *(const float4*)(wrow + k0 + kq * 4);
            int kk = kq * 4;
            Ws[kk + 0][c] = v.x; Ws[kk + 1][c] = v.y;
            Ws[kk + 2][c] = v.z; Ws[kk + 3][c] = v.w;
        }
        __syncthreads();

#pragma unroll
        for (int k = 0; k < BK; ++k) {
            float4 a  = *(const float4*)&xT[k][r0];
            float4 b0 = *(const float4*)&Ws[k][c0];
            float4 b1 = *(const float4*)&Ws[k][c0 + 4];
            const float av[4] = {a.x, a.y, a.z, a.w};
            const float bv[8] = {b0.x, b0.y, b0.z, b0.w, b1.x, b1.y, b1.z, b1.w};
#pragma unroll
            for (int i = 0; i < 4; ++i)
#pragma unroll
                for (int j = 0; j < 8; ++j) acc[i][j] += av[i] * bv[j];
        }
        __syncthreads();
    }

#pragma unroll
    for (int i = 0; i < 4; ++i) {
        int grow = rowbase + r0 + i;
        if (grow >= n) continue;
        __half* dst;
        float sc;
        if (DUAL) {
            bool isP = (c0 < OUTF);
            dst = isP ? (hp + (size_t)grow * OUTF + c0)
                      : (hn + (size_t)grow * OUTF + (c0 - OUTF));
            sc = isP ? dinvp[grow] : dinvn[grow];
        } else {
            dst = (blockIdx.y ? hn : hp) + (size_t)grow * OUTF + c0;
            sc = blockIdx.y ? dinvn[grow] : dinvp[grow];
        }
        union { __half2 h2[4]; uint4 u; } pk;
        pk.h2[0] = __floats2half2_rn(acc[i][0] * sc, acc[i][1] * sc);
        pk.h2[1] = __floats2half2_rn(acc[i][2] * sc, acc[i][3] * sc);
        pk.h2[2] = __floats2half2_rn(acc[i][4] * sc, acc[i][5] * sc);
        pk.h2[3] = __floats2half2_rn(acc[i][6] * sc, acc[i][7] * sc);
        *(uint4*)dst = pk.u;
    }
}

// ---------------------------------------------------------------------------
// Gather, F=128: one wave per target, wave-uniform scalar edge stream,
// norm pre-folded in edat.y, byte offset in edat.x, unroll x4.
// OUTPUT fp16 (feeds layer-2 GEMM).
// ---------------------------------------------------------------------------
__global__ __launch_bounds__(256) void gather128_kernel(
        const int* __restrict__ rowstart8, const int2* __restrict__ edat,
        const __half* __restrict__ hp, const __half* __restrict__ hn,
        const float* __restrict__ dinvp, const float* __restrict__ dinvn,
        const float* __restrict__ bp, const float* __restrict__ bn,
        __half* __restrict__ out, int n) {
    const int lane = threadIdx.x & 63;
    int t = (blockIdx.x * blockDim.x + threadIdx.x) >> 6;
    if (t >= n) return;
    t = __builtin_amdgcn_readfirstlane(t);
    const char* hpB = (const char*)hp;
    const char* hnB = (const char*)hn;
    int beg = rowstart8[8 * t], end = rowstart8[8 * t + 8];
    float2 acc0 = {0.f, 0.f}, acc1 = {0.f, 0.f};
    float2 acc2 = {0.f, 0.f}, acc3 = {0.f, 0.f};
    int e = beg;
    for (; e + 3 < end; e += 4) {
        int2 d0 = edat[e], d1 = edat[e + 1], d2 = edat[e + 2], d3 = edat[e + 3];
        const __half2* r0 = (const __half2*)(((d0.x & 1) ? hnB : hpB) + (d0.x & 0xFFFFFF00u));
        const __half2* r1 = (const __half2*)(((d1.x & 1) ? hnB : hpB) + (d1.x & 0xFFFFFF00u));
        const __half2* r2 = (const __half2*)(((d2.x & 1) ? hnB : hpB) + (d2.x & 0xFFFFFF00u));
        const __half2* r3 = (const __half2*)(((d3.x & 1) ? hnB : hpB) + (d3.x & 0xFFFFFF00u));
        float2 v0 = __half22float2(r0[lane]);
        float2 v1 = __half22float2(r1[lane]);
        float2 v2 = __half22float2(r2[lane]);
        float2 v3 = __half22float2(r3[lane]);
        float nv0 = __int_as_float(d0.y), nv1 = __int_as_float(d1.y);
        float nv2 = __int_as_float(d2.y), nv3 = __int_as_float(d3.y);
        acc0.x += v0.x * nv0; acc0.y += v0.y * nv0;
        acc1.x += v1.x * nv1; acc1.y += v1.y * nv1;
        acc2.x += v2.x * nv2; acc2.y += v2.y * nv2;
        acc3.x += v3.x * nv3; acc3.y += v3.y * nv3;
    }
    for (; e < end; ++e) {
        int2 d0 = edat[e];
        const __half2* r0 = (const __half2*)(((d0.x & 1) ? hnB : hpB) + (d0.x & 0xFFFFFF00u));
        float2 v0 = __half22float2(r0[lane]);
        float nv0 = __int_as_float(d0.y);
        acc0.x += v0.x * nv0; acc0.y += v0.y * nv0;
    }
    const float dp = dinvp[t], dn = dinvn[t];
    const __half2* hp2 = (const __half2*)hp;
    const __half2* hn2 = (const __half2*)hn;
    float2 hpv = __half22float2(hp2[(size_t)t * 64 + lane]);
    float2 hnv = __half22float2(hn2[(size_t)t * 64 + lane]);
    float o0 = acc0.x + acc1.x + acc2.x + acc3.x + hpv.x * dp + bp[2*lane]   - hnv.x * dn - bn[2*lane];
    float o1 = acc0.y + acc1.y + acc2.y + acc3.y + hpv.y * dp + bp[2*lane+1] - hnv.y * dn - bn[2*lane+1];
    __half2 r = __floats2half2_rn(fmaxf(o0, 0.f), fmaxf(o1, 0.f));
    *(__half2*)(out + ((size_t)t << 7) + 2 * lane) = r;
}

// Gather, F=64 (fp16 rows are 128 B: offset = (edat.x & ~255) >> 1).
// Writes fp32 directly to d_out.
__global__ __launch_bounds__(256) void gather64_kernel(
        const int* __restrict__ rowstart8, const int2* __restrict__ edat,
        const __half* __restrict__ hp, const __half* __restrict__ hn,
        const float* __restrict__ dinvp, const float* __restrict__ dinvn,
        const float* __restrict__ bp, const float* __restrict__ bn,
        float* __restrict__ out, int n) {
    const int lane = threadIdx.x & 63;
    int t = (blockIdx.x * blockDim.x + threadIdx.x) >> 6;
    if (t >= n) return;
    t = __builtin_amdgcn_readfirstlane(t);
    const char* hpB = (const char*)hp;
    const char* hnB = (const char*)hn;
    int beg = rowstart8[8 * t], end = rowstart8[8 * t + 8];
    float acc0 = 0.f, acc1 = 0.f, acc2 = 0.f, acc3 = 0.f;
    int e = beg;
    for (; e + 3 < end; e += 4) {
        int2 d0 = edat[e], d1 = edat[e + 1], d2 = edat[e + 2], d3 = edat[e + 3];
        const __half* r0 = (const __half*)(((d0.x & 1) ? hnB : hpB) + ((d0.x & 0xFFFFFF00u) >> 1));
        const __half* r1 = (const __half*)(((d1.x & 1) ? hnB : hpB) + ((d1.x & 0xFFFFFF00u) >> 1));
        const __half* r2 = (const __half*)(((d2.x & 1) ? hnB : hpB) + ((d2.x & 0xFFFFFF00u) >> 1));
        const __half* r3 = (const __half*)(((d3.x & 1) ? hnB : hpB) + ((d3.x & 0xFFFFFF00u) >> 1));
        float v0 = __half2float(r0[lane]);
        float v1 = __half2float(r1[lane]);
        float v2 = __half2float(r2[lane]);
        float v3 = __half2float(r3[lane]);
        acc0 += v0 * __int_as_float(d0.y);
        acc1 += v1 * __int_as_float(d1.y);
        acc2 += v2 * __int_as_float(d2.y);
        acc3 += v3 * __int_as_float(d3.y);
    }
    for (; e < end; ++e) {
        int2 d0 = edat[e];
        const __half* r0 = (const __half*)(((d0.x & 1) ? hnB : hpB) + ((d0.x & 0xFFFFFF00u) >> 1));
        acc0 += __half2float(r0[lane]) * __int_as_float(d0.y);
    }
    const float dp = dinvp[t], dn = dinvn[t];
    float hpv = __half2float(hp[(size_t)t * 64 + lane]);
    float hnv = __half2float(hn[(size_t)t * 64 + lane]);
    float o = acc0 + acc1 + acc2 + acc3 + hpv * dp + bp[lane] - hnv * dn - bn[lane];
    out[(size_t)t * 64 + lane] = fmaxf(o, 0.f);
}

// ---------------------------------------------------------------------------
extern "C" void kernel_launch(void* const* d_in, const int* in_sizes, int n_in,
                              void* d_out, int out_size, void* d_ws, size_t ws_size,
                              hipStream_t stream) {
    const float* x   = (const float*)d_in[0];
    const int*   ei  = (const int*)d_in[1];
    const float* ew  = (const float*)d_in[2];
    const float* W1p = (const float*)d_in[3];
    const float* b1p = (const float*)d_in[4];
    const float* W1n = (const float*)d_in[5];
    const float* b1n = (const float*)d_in[6];
    const float* W2p = (const float*)d_in[7];
    const float* b2p = (const float*)d_in[8];
    const float* W2n = (const float*)d_in[9];
    const float* b2n = (const float*)d_in[10];

    const int E = in_sizes[2];
    const int n = in_sizes[0] / 64;  // IN = 64
    const int m = REPL * n;          // scan length
    const int* src = ei;
    const int* tgt = ei + E;

    // ws layout (everything in d_ws now; d_out only holds the final result):
    //   dinvp[n]f | dinvn[n]f | blocksum[256]i | cntR[m]i | cursor[m]i |
    //   rowstart8[m+1]i | (pad to 16B) edat[E]int2 | hp1[128n]h | hn1[128n]h |
    //   h[128n]h.   layer2: hp2/hn2 (64n halves each) reuse hp1.
    float*  ws    = (float*)d_ws;
    float*  dinvp = ws;
    float*  dinvn = ws + n;
    int*    blocksum  = (int*)(ws + 2 * (size_t)n);
    int*    cntR      = blocksum + 256;
    int*    cursor    = cntR + m;
    int*    rowstart8 = cursor + m;
    size_t  off = 2 * (size_t)n + 256 + 2 * (size_t)m + (m + 2);
    off = (off + 3) & ~(size_t)3;                 // 16B-align edat
    int2*   edat = (int2*)((int*)ws + off);       // E entries (E*8 % 16 == 0)
    __half* hp1  = (__half*)(edat + E);
    __half* hn1  = hp1 + (size_t)n * 128;
    __half* h    = hn1 + (size_t)n * 128;
    __half* hp2  = hp1;
    __half* hn2  = hp1 + (size_t)n * 64;
    float*  out  = (float*)d_out;

    hipMemsetAsync(cntR, 0, (size_t)m * sizeof(int), stream);

    const int gridE2 = (E + 2 * TPB - 1) / (2 * TPB);
    const int gridN  = (n + TPB - 1) / TPB;
    const int gridW  = (n * 64 + TPB - 1) / TPB;
    const int gridM  = (n + 63) / 64;
    const int gridS  = (m + SCHUNK - 1) / SCHUNK;
    const int gridC  = (m + TPB) / TPB;

    hist_kernel<<<gridE2, TPB, 0, stream>>>(tgt, cntR, n, E);
    scan_reduce_kernel<<<gridS, TPB, 0, stream>>>(cntR, blocksum, n, m);
    scan_final_kernel<<<gridS, TPB, 0, stream>>>(cntR, blocksum, rowstart8, n, m);
    cursor_init_kernel<<<gridC, TPB, 0, stream>>>(rowstart8, cursor, m);
    fill_kernel<<<gridE2, TPB, 0, stream>>>(src, tgt, ew, cursor, edat, n, E);
    deg_dinv_kernel<<<gridN, TPB, 0, stream>>>(rowstart8, edat, dinvp, dinvn, n);

    // ---- layer 1: IN=64 -> H=128 ----
    gemm_tiled<float, 64, 128, false><<<dim3(gridM, 2), TPB, 0, stream>>>(
        x, W1p, W1n, dinvp, dinvn, hp1, hn1, n);
    gather128_kernel<<<gridW, TPB, 0, stream>>>(rowstart8, edat, hp1, hn1, dinvp, dinvn,
                                                b1p, b1n, h, n);

    // ---- layer 2: H=128 -> OUT=64 (both matrices in one BN=128 pass) ----
    gemm_tiled<__half, 128, 64, true><<<dim3(gridM, 1), TPB, 0, stream>>>(
        h, W2p, W2n, dinvp, dinvn, hp2, hn2, n);
    gather64_kernel<<<gridW, TPB, 0, stream>>>(rowstart8, edat, hp2, hn2, dinvp, dinvn,
                                               b2p, b2n, out, n);
}

// Round 10
// 567.483 us; speedup vs baseline: 1.0165x; 1.0165x over previous
//
#include <hip/hip_runtime.h>
#include <hip/hip_fp16.h>
#include <cstddef>

#define TPB 256
#define SCHUNK 4096   // scan elements per block (256 thr x 16)
#define REPL 8        // histogram/cursor replication factor
#define EPT 4         // edges per thread in hist/fill

// Replica mapping shared by hist & fill: block covers EPT*TPB edges,
// r = blockIdx & 7.  MUST be identical in both kernels (cursor capacity).
// Cursor layout is REPLICA-MAJOR cursorR[r*n+t] — R9 regression proved
// target-major puts all 8 replicas (different XCDs) in one 64B line.

// ---------------------------------------------------------------------------
// Histogram (count only), replicated; EPT edges/thread.
// ---------------------------------------------------------------------------
__global__ void hist_kernel(const int* __restrict__ tgt, int* __restrict__ cntR,
                            int n, int E) {
    const int base = blockIdx.x * (EPT * TPB) + threadIdx.x;
    int* cnt = cntR + (blockIdx.x & (REPL - 1)) * n;
#pragma unroll
    for (int j = 0; j < EPT; ++j) {
        int e = base + j * TPB;
        if (e < E) atomicAdd(&cnt[tgt[e]], 1);
    }
}

// ---------------------------------------------------------------------------
// Scan phase 1: per-chunk sums over m = 8n elements, key idx = t*8+r.
// ---------------------------------------------------------------------------
__global__ __launch_bounds__(256) void scan_reduce_kernel(
        const int* __restrict__ cntR, int* __restrict__ blocksum, int n, int m) {
    __shared__ int red[4];
    const int tid = threadIdx.x;
    const int base = blockIdx.x * SCHUNK;
    int s = 0;
    for (int i = tid; i < SCHUNK; i += 256) {
        int idx = base + i;
        if (idx < m) s += cntR[(idx & (REPL - 1)) * n + (idx >> 3)];
    }
#pragma unroll
    for (int off = 32; off; off >>= 1) s += __shfl_down(s, off, 64);
    if ((tid & 63) == 0) red[tid >> 6] = s;
    __syncthreads();
    if (tid == 0) blocksum[blockIdx.x] = red[0] + red[1] + red[2] + red[3];
}

// Scan phase 2: exclusive scan; writes t-major rowstart8 AND replica-major
// cursorR (pre-init for fill — kills fill's rowstart read, R8->R9 win kept).
__global__ __launch_bounds__(256) void scan_final_kernel(
        const int* __restrict__ cntR, const int* __restrict__ blocksum,
        int* __restrict__ rowstart8, int* __restrict__ cursorR, int n, int m) {
    __shared__ int sm[256];
    __shared__ int red[4];
    __shared__ int goff_sm;
    const int tid = threadIdx.x;
    const int b = blockIdx.x;
    int v = (tid < b) ? blocksum[tid] : 0;
#pragma unroll
    for (int off = 32; off; off >>= 1) v += __shfl_down(v, off, 64);
    if ((tid & 63) == 0) red[tid >> 6] = v;
    __syncthreads();
    if (tid == 0) goff_sm = red[0] + red[1] + red[2] + red[3];
    __syncthreads();
    const int goff = goff_sm;

    const int start = b * SCHUNK + tid * 16;
    int items[16];
    int tsum = 0;
#pragma unroll
    for (int i = 0; i < 16; ++i) {
        int idx = start + i;
        int val = (idx < m) ? cntR[(idx & (REPL - 1)) * n + (idx >> 3)] : 0;
        items[i] = tsum;
        tsum += val;
    }
    sm[tid] = tsum;
    __syncthreads();
#pragma unroll
    for (int off = 1; off < 256; off <<= 1) {
        int add = (tid >= off) ? sm[tid - off] : 0;
        __syncthreads();
        sm[tid] += add;
        __syncthreads();
    }
    const int texcl = goff + sm[tid] - tsum;
#pragma unroll
    for (int i = 0; i < 16; ++i) {
        int idx = start + i;
        if (idx < m) {
            int val = texcl + items[i];
            rowstart8[idx] = val;
            cursorR[(idx & (REPL - 1)) * n + (idx >> 3)] = val;
        }
    }
    if (b == gridDim.x - 1 && tid == 255) rowstart8[m] = goff + sm[255];
}

// ---------------------------------------------------------------------------
// Fill CSR: edat[slot] = {(src<<8)|negflag, bitcast(raw w)}; slot from the
// pre-initialized replica-major cursor (single atomic). EPT edges/thread.
// ---------------------------------------------------------------------------
__global__ void fill_kernel(const int* __restrict__ src, const int* __restrict__ tgt,
                            const float* __restrict__ ew,
                            int* __restrict__ cursorR, int2* __restrict__ edat,
                            int n, int E) {
    const int base = blockIdx.x * (EPT * TPB) + threadIdx.x;
    int* cursor = cursorR + (blockIdx.x & (REPL - 1)) * n;
#pragma unroll
    for (int j = 0; j < EPT; ++j) {
        int e = base + j * TPB;
        if (e < E) {
            int t = tgt[e], s = src[e];
            float w = ew[e];
            int pos = atomicAdd(&cursor[t], 1);
            int flag = (w < 0.0f) ? 1 : 0;
            edat[pos] = make_int2((s << 8) | flag, __float_as_int(w));
        }
    }
}

// ---------------------------------------------------------------------------
// Degrees + dinv + norm-fold: pass 1 sums |w| by sign; pass 2 rewrites
// edat.y = w * (flag ? dinvn[t] : dinvp[t])  (layer-independent norm).
// ---------------------------------------------------------------------------
__global__ void deg_dinv_kernel(const int* __restrict__ rowstart8,
                                int2* __restrict__ edat,
                                float* __restrict__ dinvp, float* __restrict__ dinvn, int n) {
    int t = blockIdx.x * blockDim.x + threadIdx.x;
    if (t >= n) return;
    int beg = rowstart8[8 * t], end = rowstart8[8 * t + 8];
    float p = 0.f, q = 0.f;
    for (int e = beg; e < end; ++e) {
        float w = __int_as_float(edat[e].y);
        p += fmaxf(w, 0.f);
        q += fmaxf(-w, 0.f);
    }
    float dp = rsqrtf(p + 1.0f), dn = rsqrtf(q + 1.0f);
    dinvp[t] = dp;
    dinvn[t] = dn;
    for (int e = beg; e < end; ++e) {
        int2 d = edat[e];
        float nv = __int_as_float(d.y) * ((d.x & 1) ? dn : dp);
        edat[e].y = __float_as_int(nv);
    }
}

// ---------------------------------------------------------------------------
// Staging load helpers (4 contiguous elems -> float4), fp32 or fp16 input.
// ---------------------------------------------------------------------------
__device__ inline float4 load4f(const float* p) { return *(const float4*)p; }
__device__ inline float4 load4f(const __half* p) {
    float2 a = __half22float2(*(const __half2*)p);
    float2 b = __half22float2(*(const __half2*)(p + 2));
    return make_float4(a.x, a.y, b.x, b.y);
}

// ---------------------------------------------------------------------------
// Tiled dual GEMM, fp32 compute, FP16 OUTPUT with dinv-scaled epilogue:
// hp' = half((X@Wp^T)*dinvp[row]).  TIN = float (layer1) or __half (layer2).
// ---------------------------------------------------------------------------
template<typename TIN, int IN, int OUTF, bool DUAL>
__global__ __launch_bounds__(256) void gemm_tiled(
        const TIN* __restrict__ x,
        const float* __restrict__ Wp, const float* __restrict__ Wn,
        const float* __restrict__ dinvp, const float* __restrict__ dinvn,
        __half* __restrict__ hp, __half* __restrict__ hn, int n) {
    constexpr int BM = 64, BN = 128, BK = 32;
    __shared__ float xT[BK][BM + 4];
    __shared__ float Ws[BK][BN + 4];

    const int tid = threadIdx.x;
    const int rowbase = blockIdx.x * BM;
    const float* __restrict__ Wsel = DUAL ? nullptr : (blockIdx.y ? Wn : Wp);

    const int r0 = (tid & 15) * 4;
    const int c0 = (tid >> 4) * 8;

    float acc[4][8];
#pragma unroll
    for (int i = 0; i < 4; ++i)
#pragma unroll
        for (int j = 0; j < 8; ++j) acc[i][j] = 0.f;

    for (int k0 = 0; k0 < IN; k0 += BK) {
#pragma unroll
        for (int i = 0; i < (BM * BK) / (4 * TPB); ++i) {
            int lin = tid + i * TPB;
            int row = lin >> 3;
            int kq  = lin & 7;
            int grow = rowbase + row;
            if (grow > n - 1) grow = n - 1;
            float4 v = load4f(x + (size_t)grow * IN + k0 + kq * 4);
            int kk = kq * 4;
            xT[kk + 0][row] = v.x; xT[kk + 1][row] = v.y;
            xT[kk + 2][row] = v.z; xT[kk + 3][row] = v.w;
        }
#pragma unroll
        for (int i = 0; i < (BN * BK) / (4 * TPB); ++i) {
            int lin = tid + i * TPB;
            int c  = lin >> 3;
            int kq = lin & 7;
            const float* wrow;
            if (DUAL) wrow = (c < OUTF) ? (Wp + (size_t)c * IN) : (Wn + (size_t)(c - OUTF) * IN);
            else      wrow = Wsel + (size_t)c * IN;
            float4 v = *(const float4*)(wrow + k0 + kq * 4);
            int kk = kq * 4;
            Ws[kk + 0][c] = v.x; Ws[kk + 1][c] = v.y;
            Ws[kk + 2][c] = v.z; Ws[kk + 3][c] = v.w;
        }
        __syncthreads();

#pragma unroll
        for (int k = 0; k < BK; ++k) {
            float4 a  = *(const float4*)&xT[k][r0];
            float4 b0 = *(const float4*)&Ws[k][c0];
            float4 b1 = *(const float4*)&Ws[k][c0 + 4];
            const float av[4] = {a.x, a.y, a.z, a.w};
            const float bv[8] = {b0.x, b0.y, b0.z, b0.w, b1.x, b1.y, b1.z, b1.w};
#pragma unroll
            for (int i = 0; i < 4; ++i)
#pragma unroll
                for (int j = 0; j < 8; ++j) acc[i][j] += av[i] * bv[j];
        }
        __syncthreads();
    }

#pragma unroll
    for (int i = 0; i < 4; ++i) {
        int grow = rowbase + r0 + i;
        if (grow >= n) continue;
        __half* dst;
        float sc;
        if (DUAL) {
            bool isP = (c0 < OUTF);
            dst = isP ? (hp + (size_t)grow * OUTF + c0)
                      : (hn + (size_t)grow * OUTF + (c0 - OUTF));
            sc = isP ? dinvp[grow] : dinvn[grow];
        } else {
            dst = (blockIdx.y ? hn : hp) + (size_t)grow * OUTF + c0;
            sc = blockIdx.y ? dinvn[grow] : dinvp[grow];
        }
        union { __half2 h2[4]; uint4 u; } pk;
        pk.h2[0] = __floats2half2_rn(acc[i][0] * sc, acc[i][1] * sc);
        pk.h2[1] = __floats2half2_rn(acc[i][2] * sc, acc[i][3] * sc);
        pk.h2[2] = __floats2half2_rn(acc[i][4] * sc, acc[i][5] * sc);
        pk.h2[3] = __floats2half2_rn(acc[i][6] * sc, acc[i][7] * sc);
        *(uint4*)dst = pk.u;
    }
}

// ---------------------------------------------------------------------------
// Gather, F=128: one wave per target, wave-uniform scalar edge stream,
// norm pre-folded in edat.y, byte offset in edat.x, unroll x4.
// OUTPUT fp16 (feeds layer-2 GEMM).
// ---------------------------------------------------------------------------
__global__ __launch_bounds__(256) void gather128_kernel(
        const int* __restrict__ rowstart8, const int2* __restrict__ edat,
        const __half* __restrict__ hp, const __half* __restrict__ hn,
        const float* __restrict__ dinvp, const float* __restrict__ dinvn,
        const float* __restrict__ bp, const float* __restrict__ bn,
        __half* __restrict__ out, int n) {
    const int lane = threadIdx.x & 63;
    int t = (blockIdx.x * blockDim.x + threadIdx.x) >> 6;
    if (t >= n) return;
    t = __builtin_amdgcn_readfirstlane(t);
    const char* hpB = (const char*)hp;
    const char* hnB = (const char*)hn;
    int beg = rowstart8[8 * t], end = rowstart8[8 * t + 8];
    float2 acc0 = {0.f, 0.f}, acc1 = {0.f, 0.f};
    float2 acc2 = {0.f, 0.f}, acc3 = {0.f, 0.f};
    int e = beg;
    for (; e + 3 < end; e += 4) {
        int2 d0 = edat[e], d1 = edat[e + 1], d2 = edat[e + 2], d3 = edat[e + 3];
        const __half2* r0 = (const __half2*)(((d0.x & 1) ? hnB : hpB) + (d0.x & 0xFFFFFF00u));
        const __half2* r1 = (const __half2*)(((d1.x & 1) ? hnB : hpB) + (d1.x & 0xFFFFFF00u));
        const __half2* r2 = (const __half2*)(((d2.x & 1) ? hnB : hpB) + (d2.x & 0xFFFFFF00u));
        const __half2* r3 = (const __half2*)(((d3.x & 1) ? hnB : hpB) + (d3.x & 0xFFFFFF00u));
        float2 v0 = __half22float2(r0[lane]);
        float2 v1 = __half22float2(r1[lane]);
        float2 v2 = __half22float2(r2[lane]);
        float2 v3 = __half22float2(r3[lane]);
        float nv0 = __int_as_float(d0.y), nv1 = __int_as_float(d1.y);
        float nv2 = __int_as_float(d2.y), nv3 = __int_as_float(d3.y);
        acc0.x += v0.x * nv0; acc0.y += v0.y * nv0;
        acc1.x += v1.x * nv1; acc1.y += v1.y * nv1;
        acc2.x += v2.x * nv2; acc2.y += v2.y * nv2;
        acc3.x += v3.x * nv3; acc3.y += v3.y * nv3;
    }
    for (; e < end; ++e) {
        int2 d0 = edat[e];
        const __half2* r0 = (const __half2*)(((d0.x & 1) ? hnB : hpB) + (d0.x & 0xFFFFFF00u));
        float2 v0 = __half22float2(r0[lane]);
        float nv0 = __int_as_float(d0.y);
        acc0.x += v0.x * nv0; acc0.y += v0.y * nv0;
    }
    const float dp = dinvp[t], dn = dinvn[t];
    const __half2* hp2 = (const __half2*)hp;
    const __half2* hn2 = (const __half2*)hn;
    float2 hpv = __half22float2(hp2[(size_t)t * 64 + lane]);
    float2 hnv = __half22float2(hn2[(size_t)t * 64 + lane]);
    float o0 = acc0.x + acc1.x + acc2.x + acc3.x + hpv.x * dp + bp[2*lane]   - hnv.x * dn - bn[2*lane];
    float o1 = acc0.y + acc1.y + acc2.y + acc3.y + hpv.y * dp + bp[2*lane+1] - hnv.y * dn - bn[2*lane+1];
    __half2 r = __floats2half2_rn(fmaxf(o0, 0.f), fmaxf(o1, 0.f));
    *(__half2*)(out + ((size_t)t << 7) + 2 * lane) = r;
}

// Gather, F=64 (fp16 rows are 128 B: offset = (edat.x & ~255) >> 1).
// Writes fp32 directly to d_out.
__global__ __launch_bounds__(256) void gather64_kernel(
        const int* __restrict__ rowstart8, const int2* __restrict__ edat,
        const __half* __restrict__ hp, const __half* __restrict__ hn,
        const float* __restrict__ dinvp, const float* __restrict__ dinvn,
        const float* __restrict__ bp, const float* __restrict__ bn,
        float* __restrict__ out, int n) {
    const int lane = threadIdx.x & 63;
    int t = (blockIdx.x * blockDim.x + threadIdx.x) >> 6;
    if (t >= n) return;
    t = __builtin_amdgcn_readfirstlane(t);
    const char* hpB = (const char*)hp;
    const char* hnB = (const char*)hn;
    int beg = rowstart8[8 * t], end = rowstart8[8 * t + 8];
    float acc0 = 0.f, acc1 = 0.f, acc2 = 0.f, acc3 = 0.f;
    int e = beg;
    for (; e + 3 < end; e += 4) {
        int2 d0 = edat[e], d1 = edat[e + 1], d2 = edat[e + 2], d3 = edat[e + 3];
        const __half* r0 = (const __half*)(((d0.x & 1) ? hnB : hpB) + ((d0.x & 0xFFFFFF00u) >> 1));
        const __half* r1 = (const __half*)(((d1.x & 1) ? hnB : hpB) + ((d1.x & 0xFFFFFF00u) >> 1));
        const __half* r2 = (const __half*)(((d2.x & 1) ? hnB : hpB) + ((d2.x & 0xFFFFFF00u) >> 1));
        const __half* r3 = (const __half*)(((d3.x & 1) ? hnB : hpB) + ((d3.x & 0xFFFFFF00u) >> 1));
        float v0 = __half2float(r0[lane]);
        float v1 = __half2float(r1[lane]);
        float v2 = __half2float(r2[lane]);
        float v3 = __half2float(r3[lane]);
        acc0 += v0 * __int_as_float(d0.y);
        acc1 += v1 * __int_as_float(d1.y);
        acc2 += v2 * __int_as_float(d2.y);
        acc3 += v3 * __int_as_float(d3.y);
    }
    for (; e < end; ++e) {
        int2 d0 = edat[e];
        const __half* r0 = (const __half*)(((d0.x & 1) ? hnB : hpB) + ((d0.x & 0xFFFFFF00u) >> 1));
        acc0 += __half2float(r0[lane]) * __int_as_float(d0.y);
    }
    const float dp = dinvp[t], dn = dinvn[t];
    float hpv = __half2float(hp[(size_t)t * 64 + lane]);
    float hnv = __half2float(hn[(size_t)t * 64 + lane]);
    float o = acc0 + acc1 + acc2 + acc3 + hpv * dp + bp[lane] - hnv * dn - bn[lane];
    out[(size_t)t * 64 + lane] = fmaxf(o, 0.f);
}

// ---------------------------------------------------------------------------
extern "C" void kernel_launch(void* const* d_in, const int* in_sizes, int n_in,
                              void* d_out, int out_size, void* d_ws, size_t ws_size,
                              hipStream_t stream) {
    const float* x   = (const float*)d_in[0];
    const int*   ei  = (const int*)d_in[1];
    const float* ew  = (const float*)d_in[2];
    const float* W1p = (const float*)d_in[3];
    const float* b1p = (const float*)d_in[4];
    const float* W1n = (const float*)d_in[5];
    const float* b1n = (const float*)d_in[6];
    const float* W2p = (const float*)d_in[7];
    const float* b2p = (const float*)d_in[8];
    const float* W2n = (const float*)d_in[9];
    const float* b2n = (const float*)d_in[10];

    const int E = in_sizes[2];
    const int n = in_sizes[0] / 64;  // IN = 64
    const int m = REPL * n;          // scan length
    const int* src = ei;
    const int* tgt = ei + E;

    // ws layout: dinvp[n]f | dinvn[n]f | blocksum[256]i | cntR[m]i |
    //   cursorR[m]i | rowstart8[m+1]i | (align) edat[E]int2 | hp1[128n]h |
    //   hn1[128n]h | h[128n]h.  layer2: hp2/hn2 reuse hp1.
    float*  ws    = (float*)d_ws;
    float*  dinvp = ws;
    float*  dinvn = ws + n;
    int*    blocksum  = (int*)(ws + 2 * (size_t)n);
    int*    cntR      = blocksum + 256;
    int*    cursorR   = cntR + m;
    int*    rowstart8 = cursorR + m;
    size_t  off = 2 * (size_t)n + 256 + 2 * (size_t)m + (m + 2);
    off = (off + 3) & ~(size_t)3;                 // 16B-align edat
    int2*   edat = (int2*)((int*)ws + off);
    __half* hp1  = (__half*)(edat + E);
    __half* hn1  = hp1 + (size_t)n * 128;
    __half* h    = hn1 + (size_t)n * 128;
    __half* hp2  = hp1;
    __half* hn2  = hp1 + (size_t)n * 64;
    float*  out  = (float*)d_out;

    hipMemsetAsync(cntR, 0, (size_t)m * sizeof(int), stream);

    const int gridE4 = (E + EPT * TPB - 1) / (EPT * TPB);
    const int gridN  = (n + TPB - 1) / TPB;
    const int gridW  = (n * 64 + TPB - 1) / TPB;
    const int gridM  = (n + 63) / 64;
    const int gridS  = (m + SCHUNK - 1) / SCHUNK;

    hist_kernel<<<gridE4, TPB, 0, stream>>>(tgt, cntR, n, E);
    scan_reduce_kernel<<<gridS, TPB, 0, stream>>>(cntR, blocksum, n, m);
    scan_final_kernel<<<gridS, TPB, 0, stream>>>(cntR, blocksum, rowstart8, cursorR, n, m);
    fill_kernel<<<gridE4, TPB, 0, stream>>>(src, tgt, ew, cursorR, edat, n, E);
    deg_dinv_kernel<<<gridN, TPB, 0, stream>>>(rowstart8, edat, dinvp, dinvn, n);

    // ---- layer 1: IN=64 -> H=128 ----
    gemm_tiled<float, 64, 128, false><<<dim3(gridM, 2), TPB, 0, stream>>>(
        x, W1p, W1n, dinvp, dinvn, hp1, hn1, n);
    gather128_kernel<<<gridW, TPB, 0, stream>>>(rowstart8, edat, hp1, hn1, dinvp, dinvn,
                                                b1p, b1n, h, n);

    // ---- layer 2: H=128 -> OUT=64 (both matrices in one BN=128 pass) ----
    gemm_tiled<__half, 128, 64, true><<<dim3(gridM, 1), TPB, 0, stream>>>(
        h, W2p, W2n, dinvp, dinvn, hp2, hn2, n);
    gather64_kernel<<<gridW, TPB, 0, stream>>>(rowstart8, edat, hp2, hn2, dinvp, dinvn,
                                               b2p, b2n, out, n);
}

// Round 11
// 441.500 us; speedup vs baseline: 1.3065x; 1.2854x over previous
//
#include <hip/hip_runtime.h>
#include <hip/hip_fp16.h>
#include <cstddef>

#define TPB 256
#define BSH 9            // log2(targets per bucket)
#define BTGT 512         // targets per bucket (nb = ceil(n/512) <= 256 for n <= 131072)
#define EPA 8            // edges per thread in A0/A
#define ACHUNK (EPA * TPB)

// ---------------------------------------------------------------------------
// A0: per-bucket edge counts. LDS-aggregated; one padded global atomic per
// (block, bucket) — padding (16 ints = 64B) gives each counter its own line.
// ---------------------------------------------------------------------------
__global__ __launch_bounds__(256) void bucket_count_kernel(
        const int* __restrict__ tgt, int* __restrict__ cnt_pad, int E) {
    __shared__ int lcnt[256];
    const int tid = threadIdx.x;
    lcnt[tid] = 0;
    __syncthreads();
    const int base = blockIdx.x * ACHUNK + tid;
#pragma unroll
    for (int j = 0; j < EPA; ++j) {
        int e = base + j * TPB;
        if (e < E) atomicAdd(&lcnt[tgt[e] >> BSH], 1);
    }
    __syncthreads();
    if (lcnt[tid]) atomicAdd(&cnt_pad[tid * 16], lcnt[tid]);
}

// ---------------------------------------------------------------------------
// scanTot: exclusive scan of bucket totals -> bucket_start[nb+1]; also
// initializes the padded pass-A cursors to the bucket starts.
// ---------------------------------------------------------------------------
__global__ __launch_bounds__(256) void bucket_scan_kernel(
        const int* __restrict__ cnt_pad, int* __restrict__ bucket_start,
        int* __restrict__ cursor_pad, int nb, int E) {
    __shared__ int sm[256];
    const int tid = threadIdx.x;
    int v = (tid < nb) ? cnt_pad[tid * 16] : 0;
    const int orig = v;
    sm[tid] = v;
    __syncthreads();
#pragma unroll
    for (int off = 1; off < 256; off <<= 1) {
        int add = (tid >= off) ? sm[tid - off] : 0;
        __syncthreads();
        sm[tid] += add;
        __syncthreads();
    }
    int excl = sm[tid] - orig;
    if (tid < nb) {
        bucket_start[tid] = excl;
        cursor_pad[tid * 16] = excl;
    }
    if (tid == 0) bucket_start[nb] = E;
}

// ---------------------------------------------------------------------------
// A: bucket scatter. LDS histogram assigns each edge a local rank; one padded
// global atomic per (block,bucket) reserves a contiguous run; records land in
// ~contiguous runs per bucket (low write amplification vs per-edge scatter).
// rec = {t, (src<<8)|negflag, bitcast(w), 0}
// ---------------------------------------------------------------------------
__global__ __launch_bounds__(256) void bucket_scatter_kernel(
        const int* __restrict__ tgt, const int* __restrict__ src,
        const float* __restrict__ ew, int* __restrict__ cursor_pad,
        int4* __restrict__ recs, int E) {
    __shared__ int lcnt[256];
    __shared__ int lbase[256];
    const int tid = threadIdx.x;
    lcnt[tid] = 0;
    __syncthreads();
    const int base = blockIdx.x * ACHUNK + tid;
    int mt[EPA], ms[EPA], mr[EPA];
    float mw[EPA];
#pragma unroll
    for (int j = 0; j < EPA; ++j) {
        int e = base + j * TPB;
        if (e < E) {
            mt[j] = tgt[e];
            ms[j] = src[e];
            mw[j] = ew[e];
            mr[j] = atomicAdd(&lcnt[mt[j] >> BSH], 1);
        }
    }
    __syncthreads();
    if (lcnt[tid]) lbase[tid] = atomicAdd(&cursor_pad[tid * 16], lcnt[tid]);
    __syncthreads();
#pragma unroll
    for (int j = 0; j < EPA; ++j) {
        int e = base + j * TPB;
        if (e < E) {
            int b = mt[j] >> BSH;
            int pos = lbase[b] + mr[j];
            int flag = (mw[j] < 0.0f) ? 1 : 0;
            recs[pos] = make_int4(mt[j], (ms[j] << 8) | flag,
                                  __float_as_int(mw[j]), 0);
        }
    }
}

// ---------------------------------------------------------------------------
// B: per-bucket CSR build. One block owns one bucket (targets [b*512, ...)),
// whose edges sit in one contiguous ~65KB region: LDS hist (512 bins) ->
// LDS scan -> coalesced rowstart write -> LDS-atomic ranked placement.
// edat stores stay inside the bucket's region (L2-local, ~1x amplification).
// Zero global atomics.
// ---------------------------------------------------------------------------
__global__ __launch_bounds__(256) void csr_build_kernel(
        const int* __restrict__ bucket_start, const int4* __restrict__ recs,
        int* __restrict__ rowstart, int2* __restrict__ edat,
        int n, int nb, int E) {
    __shared__ int h[BTGT];
    __shared__ int cur[BTGT];
    __shared__ int sm[256];
    const int b = blockIdx.x, tid = threadIdx.x;
    const int beg = bucket_start[b], end = bucket_start[b + 1];
    h[tid] = 0;
    h[tid + 256] = 0;
    __syncthreads();
    for (int i = beg + tid; i < end; i += 256) {
        int4 r = recs[i];
        atomicAdd(&h[r.x & (BTGT - 1)], 1);
    }
    __syncthreads();
    // exclusive scan of 512 via 256-thread pair scan
    int pairsum = h[2 * tid] + h[2 * tid + 1];
    sm[tid] = pairsum;
    __syncthreads();
#pragma unroll
    for (int off = 1; off < 256; off <<= 1) {
        int add = (tid >= off) ? sm[tid - off] : 0;
        __syncthreads();
        sm[tid] += add;
        __syncthreads();
    }
    int epair = sm[tid] - pairsum;
    cur[2 * tid]     = epair;
    cur[2 * tid + 1] = epair + h[2 * tid];
    __syncthreads();
    const int t0 = b << BSH;
    for (int j = tid; j < BTGT; j += 256) {
        int t = t0 + j;
        if (t < n) rowstart[t] = beg + cur[j];
    }
    if (b == nb - 1 && tid == 0) rowstart[n] = E;
    __syncthreads();
    for (int i = beg + tid; i < end; i += 256) {
        int4 r = recs[i];
        int rank = atomicAdd(&cur[r.x & (BTGT - 1)], 1);
        edat[beg + rank] = make_int2(r.y, r.z);
    }
}

// ---------------------------------------------------------------------------
// Degrees + dinv + norm-fold: pass 1 sums |w| by sign; pass 2 rewrites
// edat.y = w * (flag ? dinvn[t] : dinvp[t])  (layer-independent norm).
// ---------------------------------------------------------------------------
__global__ void deg_dinv_kernel(const int* __restrict__ rowstart,
                                int2* __restrict__ edat,
                                float* __restrict__ dinvp, float* __restrict__ dinvn, int n) {
    int t = blockIdx.x * blockDim.x + threadIdx.x;
    if (t >= n) return;
    int beg = rowstart[t], end = rowstart[t + 1];
    float p = 0.f, q = 0.f;
    for (int e = beg; e < end; ++e) {
        float w = __int_as_float(edat[e].y);
        p += fmaxf(w, 0.f);
        q += fmaxf(-w, 0.f);
    }
    float dp = rsqrtf(p + 1.0f), dn = rsqrtf(q + 1.0f);
    dinvp[t] = dp;
    dinvn[t] = dn;
    for (int e = beg; e < end; ++e) {
        int2 d = edat[e];
        float nv = __int_as_float(d.y) * ((d.x & 1) ? dn : dp);
        edat[e].y = __float_as_int(nv);
    }
}

// ---------------------------------------------------------------------------
// Staging load helpers (4 contiguous elems -> float4), fp32 or fp16 input.
// ---------------------------------------------------------------------------
__device__ inline float4 load4f(const float* p) { return *(const float4*)p; }
__device__ inline float4 load4f(const __half* p) {
    float2 a = __half22float2(*(const __half2*)p);
    float2 b = __half22float2(*(const __half2*)(p + 2));
    return make_float4(a.x, a.y, b.x, b.y);
}

// ---------------------------------------------------------------------------
// Tiled dual GEMM, fp32 compute, FP16 OUTPUT with dinv-scaled epilogue:
// hp' = half((X@Wp^T)*dinvp[row]).  TIN = float (layer1) or __half (layer2).
// ---------------------------------------------------------------------------
template<typename TIN, int IN, int OUTF, bool DUAL>
__global__ __launch_bounds__(256) void gemm_tiled(
        const TIN* __restrict__ x,
        const float* __restrict__ Wp, const float* __restrict__ Wn,
        const float* __restrict__ dinvp, const float* __restrict__ dinvn,
        __half* __restrict__ hp, __half* __restrict__ hn, int n) {
    constexpr int BM = 64, BN = 128, BK = 32;
    __shared__ float xT[BK][BM + 4];
    __shared__ float Ws[BK][BN + 4];

    const int tid = threadIdx.x;
    const int rowbase = blockIdx.x * BM;
    const float* __restrict__ Wsel = DUAL ? nullptr : (blockIdx.y ? Wn : Wp);

    const int r0 = (tid & 15) * 4;
    const int c0 = (tid >> 4) * 8;

    float acc[4][8];
#pragma unroll
    for (int i = 0; i < 4; ++i)
#pragma unroll
        for (int j = 0; j < 8; ++j) acc[i][j] = 0.f;

    for (int k0 = 0; k0 < IN; k0 += BK) {
#pragma unroll
        for (int i = 0; i < (BM * BK) / (4 * TPB); ++i) {
            int lin = tid + i * TPB;
            int row = lin >> 3;
            int kq  = lin & 7;
            int grow = rowbase + row;
            if (grow > n - 1) grow = n - 1;
            float4 v = load4f(x + (size_t)grow * IN + k0 + kq * 4);
            int kk = kq * 4;
            xT[kk + 0][row] = v.x; xT[kk + 1][row] = v.y;
            xT[kk + 2][row] = v.z; xT[kk + 3][row] = v.w;
        }
#pragma unroll
        for (int i = 0; i < (BN * BK) / (4 * TPB); ++i) {
            int lin = tid + i * TPB;
            int c  = lin >> 3;
            int kq = lin & 7;
            const float* wrow;
            if (DUAL) wrow = (c < OUTF) ? (Wp + (size_t)c * IN) : (Wn + (size_t)(c - OUTF) * IN);
            else      wrow = Wsel + (size_t)c * IN;
            float4 v = *(const float4*)(wrow + k0 + kq * 4);
            int kk = kq * 4;
            Ws[kk + 0][c] = v.x; Ws[kk + 1][c] = v.y;
            Ws[kk + 2][c] = v.z; Ws[kk + 3][c] = v.w;
        }
        __syncthreads();

#pragma unroll
        for (int k = 0; k < BK; ++k) {
            float4 a  = *(const float4*)&xT[k][r0];
            float4 b0 = *(const float4*)&Ws[k][c0];
            float4 b1 = *(const float4*)&Ws[k][c0 + 4];
            const float av[4] = {a.x, a.y, a.z, a.w};
            const float bv[8] = {b0.x, b0.y, b0.z, b0.w, b1.x, b1.y, b1.z, b1.w};
#pragma unroll
            for (int i = 0; i < 4; ++i)
#pragma unroll
                for (int j = 0; j < 8; ++j) acc[i][j] += av[i] * bv[j];
        }
        __syncthreads();
    }

#pragma unroll
    for (int i = 0; i < 4; ++i) {
        int grow = rowbase + r0 + i;
        if (grow >= n) continue;
        __half* dst;
        float sc;
        if (DUAL) {
            bool isP = (c0 < OUTF);
            dst = isP ? (hp + (size_t)grow * OUTF + c0)
                      : (hn + (size_t)grow * OUTF + (c0 - OUTF));
            sc = isP ? dinvp[grow] : dinvn[grow];
        } else {
            dst = (blockIdx.y ? hn : hp) + (size_t)grow * OUTF + c0;
            sc = blockIdx.y ? dinvn[grow] : dinvp[grow];
        }
        union { __half2 h2[4]; uint4 u; } pk;
        pk.h2[0] = __floats2half2_rn(acc[i][0] * sc, acc[i][1] * sc);
        pk.h2[1] = __floats2half2_rn(acc[i][2] * sc, acc[i][3] * sc);
        pk.h2[2] = __floats2half2_rn(acc[i][4] * sc, acc[i][5] * sc);
        pk.h2[3] = __floats2half2_rn(acc[i][6] * sc, acc[i][7] * sc);
        *(uint4*)dst = pk.u;
    }
}

// ---------------------------------------------------------------------------
// Gather, F=128: one wave per target, wave-uniform scalar edge stream,
// norm pre-folded in edat.y, byte offset in edat.x, unroll x4.
// OUTPUT fp16 (feeds layer-2 GEMM).
// ---------------------------------------------------------------------------
__global__ __launch_bounds__(256) void gather128_kernel(
        const int* __restrict__ rowstart, const int2* __restrict__ edat,
        const __half* __restrict__ hp, const __half* __restrict__ hn,
        const float* __restrict__ dinvp, const float* __restrict__ dinvn,
        const float* __restrict__ bp, const float* __restrict__ bn,
        __half* __restrict__ out, int n) {
    const int lane = threadIdx.x & 63;
    int t = (blockIdx.x * blockDim.x + threadIdx.x) >> 6;
    if (t >= n) return;
    t = __builtin_amdgcn_readfirstlane(t);
    const char* hpB = (const char*)hp;
    const char* hnB = (const char*)hn;
    int beg = rowstart[t], end = rowstart[t + 1];
    float2 acc0 = {0.f, 0.f}, acc1 = {0.f, 0.f};
    float2 acc2 = {0.f, 0.f}, acc3 = {0.f, 0.f};
    int e = beg;
    for (; e + 3 < end; e += 4) {
        int2 d0 = edat[e], d1 = edat[e + 1], d2 = edat[e + 2], d3 = edat[e + 3];
        const __half2* r0 = (const __half2*)(((d0.x & 1) ? hnB : hpB) + (d0.x & 0xFFFFFF00u));
        const __half2* r1 = (const __half2*)(((d1.x & 1) ? hnB : hpB) + (d1.x & 0xFFFFFF00u));
        const __half2* r2 = (const __half2*)(((d2.x & 1) ? hnB : hpB) + (d2.x & 0xFFFFFF00u));
        const __half2* r3 = (const __half2*)(((d3.x & 1) ? hnB : hpB) + (d3.x & 0xFFFFFF00u));
        float2 v0 = __half22float2(r0[lane]);
        float2 v1 = __half22float2(r1[lane]);
        float2 v2 = __half22float2(r2[lane]);
        float2 v3 = __half22float2(r3[lane]);
        float nv0 = __int_as_float(d0.y), nv1 = __int_as_float(d1.y);
        float nv2 = __int_as_float(d2.y), nv3 = __int_as_float(d3.y);
        acc0.x += v0.x * nv0; acc0.y += v0.y * nv0;
        acc1.x += v1.x * nv1; acc1.y += v1.y * nv1;
        acc2.x += v2.x * nv2; acc2.y += v2.y * nv2;
        acc3.x += v3.x * nv3; acc3.y += v3.y * nv3;
    }
    for (; e < end; ++e) {
        int2 d0 = edat[e];
        const __half2* r0 = (const __half2*)(((d0.x & 1) ? hnB : hpB) + (d0.x & 0xFFFFFF00u));
        float2 v0 = __half22float2(r0[lane]);
        float nv0 = __int_as_float(d0.y);
        acc0.x += v0.x * nv0; acc0.y += v0.y * nv0;
    }
    const float dp = dinvp[t], dn = dinvn[t];
    const __half2* hp2 = (const __half2*)hp;
    const __half2* hn2 = (const __half2*)hn;
    float2 hpv = __half22float2(hp2[(size_t)t * 64 + lane]);
    float2 hnv = __half22float2(hn2[(size_t)t * 64 + lane]);
    float o0 = acc0.x + acc1.x + acc2.x + acc3.x + hpv.x * dp + bp[2*lane]   - hnv.x * dn - bn[2*lane];
    float o1 = acc0.y + acc1.y + acc2.y + acc3.y + hpv.y * dp + bp[2*lane+1] - hnv.y * dn - bn[2*lane+1];
    __half2 r = __floats2half2_rn(fmaxf(o0, 0.f), fmaxf(o1, 0.f));
    *(__half2*)(out + ((size_t)t << 7) + 2 * lane) = r;
}

// Gather, F=64 (fp16 rows are 128 B: offset = (edat.x & ~255) >> 1).
// Writes fp32 directly to d_out.
__global__ __launch_bounds__(256) void gather64_kernel(
        const int* __restrict__ rowstart, const int2* __restrict__ edat,
        const __half* __restrict__ hp, const __half* __restrict__ hn,
        const float* __restrict__ dinvp, const float* __restrict__ dinvn,
        const float* __restrict__ bp, const float* __restrict__ bn,
        float* __restrict__ out, int n) {
    const int lane = threadIdx.x & 63;
    int t = (blockIdx.x * blockDim.x + threadIdx.x) >> 6;
    if (t >= n) return;
    t = __builtin_amdgcn_readfirstlane(t);
    const char* hpB = (const char*)hp;
    const char* hnB = (const char*)hn;
    int beg = rowstart[t], end = rowstart[t + 1];
    float acc0 = 0.f, acc1 = 0.f, acc2 = 0.f, acc3 = 0.f;
    int e = beg;
    for (; e + 3 < end; e += 4) {
        int2 d0 = edat[e], d1 = edat[e + 1], d2 = edat[e + 2], d3 = edat[e + 3];
        const __half* r0 = (const __half*)(((d0.x & 1) ? hnB : hpB) + ((d0.x & 0xFFFFFF00u) >> 1));
        const __half* r1 = (const __half*)(((d1.x & 1) ? hnB : hpB) + ((d1.x & 0xFFFFFF00u) >> 1));
        const __half* r2 = (const __half*)(((d2.x & 1) ? hnB : hpB) + ((d2.x & 0xFFFFFF00u) >> 1));
        const __half* r3 = (const __half*)(((d3.x & 1) ? hnB : hpB) + ((d3.x & 0xFFFFFF00u) >> 1));
        float v0 = __half2float(r0[lane]);
        float v1 = __half2float(r1[lane]);
        float v2 = __half2float(r2[lane]);
        float v3 = __half2float(r3[lane]);
        acc0 += v0 * __int_as_float(d0.y);
        acc1 += v1 * __int_as_float(d1.y);
        acc2 += v2 * __int_as_float(d2.y);
        acc3 += v3 * __int_as_float(d3.y);
    }
    for (; e < end; ++e) {
        int2 d0 = edat[e];
        const __half* r0 = (const __half*)(((d0.x & 1) ? hnB : hpB) + ((d0.x & 0xFFFFFF00u) >> 1));
        acc0 += __half2float(r0[lane]) * __int_as_float(d0.y);
    }
    const float dp = dinvp[t], dn = dinvn[t];
    float hpv = __half2float(hp[(size_t)t * 64 + lane]);
    float hnv = __half2float(hn[(size_t)t * 64 + lane]);
    float o = acc0 + acc1 + acc2 + acc3 + hpv * dp + bp[lane] - hnv * dn - bn[lane];
    out[(size_t)t * 64 + lane] = fmaxf(o, 0.f);
}

// ---------------------------------------------------------------------------
extern "C" void kernel_launch(void* const* d_in, const int* in_sizes, int n_in,
                              void* d_out, int out_size, void* d_ws, size_t ws_size,
                              hipStream_t stream) {
    const float* x   = (const float*)d_in[0];
    const int*   ei  = (const int*)d_in[1];
    const float* ew  = (const float*)d_in[2];
    const float* W1p = (const float*)d_in[3];
    const float* b1p = (const float*)d_in[4];
    const float* W1n = (const float*)d_in[5];
    const float* b1n = (const float*)d_in[6];
    const float* W2p = (const float*)d_in[7];
    const float* b2p = (const float*)d_in[8];
    const float* W2n = (const float*)d_in[9];
    const float* b2n = (const float*)d_in[10];

    const int E = in_sizes[2];
    const int n = in_sizes[0] / 64;  // IN = 64
    const int nb = (n + BTGT - 1) >> BSH;   // buckets (<=256 for n<=131072)
    const int* src = ei;
    const int* tgt = ei + E;

    // ws (4B units): cnt_pad[4096] | cursor_pad[4096] | bucket_start[257] |
    //   dinvp[n]f | dinvn[n]f | rowstart[n+1] | (align16) recs[E]int4 |
    //   edat[E]int2 | hp1[128n]h | hn1[128n]h | h[128n]h.
    //   layer2: hp2/hn2 reuse hp1.  Total ~116 MB.
    int*    wsi        = (int*)d_ws;
    int*    cnt_pad    = wsi;
    int*    cursor_pad = wsi + 4096;
    int*    bucket_start = wsi + 8192;
    float*  dinvp      = (float*)(wsi + 8192 + 257);
    float*  dinvn      = dinvp + n;
    int*    rowstart   = (int*)(dinvn + n);
    size_t  off = (size_t)(8192 + 257) + 2 * (size_t)n + (n + 1);
    off = (off + 3) & ~(size_t)3;                 // 16B-align recs
    int4*   recs = (int4*)(wsi + off);
    int2*   edat = (int2*)(recs + E);
    __half* hp1  = (__half*)(edat + E);
    __half* hn1  = hp1 + (size_t)n * 128;
    __half* h    = hn1 + (size_t)n * 128;
    __half* hp2  = hp1;
    __half* hn2  = hp1 + (size_t)n * 64;
    float*  out  = (float*)d_out;

    hipMemsetAsync(cnt_pad, 0, 4096 * sizeof(int), stream);

    const int gridA = (E + ACHUNK - 1) / ACHUNK;
    const int gridN = (n + TPB - 1) / TPB;
    const int gridW = (n * 64 + TPB - 1) / TPB;
    const int gridM = (n + 63) / 64;

    bucket_count_kernel<<<gridA, TPB, 0, stream>>>(tgt, cnt_pad, E);
    bucket_scan_kernel<<<1, TPB, 0, stream>>>(cnt_pad, bucket_start, cursor_pad, nb, E);
    bucket_scatter_kernel<<<gridA, TPB, 0, stream>>>(tgt, src, ew, cursor_pad, recs, E);
    csr_build_kernel<<<nb, TPB, 0, stream>>>(bucket_start, recs, rowstart, edat, n, nb, E);
    deg_dinv_kernel<<<gridN, TPB, 0, stream>>>(rowstart, edat, dinvp, dinvn, n);

    // ---- layer 1: IN=64 -> H=128 ----
    gemm_tiled<float, 64, 128, false><<<dim3(gridM, 2), TPB, 0, stream>>>(
        x, W1p, W1n, dinvp, dinvn, hp1, hn1, n);
    gather128_kernel<<<gridW, TPB, 0, stream>>>(rowstart, edat, hp1, hn1, dinvp, dinvn,
                                                b1p, b1n, h, n);

    // ---- layer 2: H=128 -> OUT=64 (both matrices in one BN=128 pass) ----
    gemm_tiled<__half, 128, 64, true><<<dim3(gridM, 1), TPB, 0, stream>>>(
        h, W2p, W2n, dinvp, dinvn, hp2, hn2, n);
    gather64_kernel<<<gridW, TPB, 0, stream>>>(rowstart, edat, hp2, hn2, dinvp, dinvn,
                                               b2p, b2n, out, n);
}

// Round 12
// 416.105 us; speedup vs baseline: 1.3863x; 1.0610x over previous
//
#include <hip/hip_runtime.h>
#include <hip/hip_fp16.h>
#include <cstddef>

#define TPB 256
#define BSH 9            // log2(targets per bucket)
#define BTGT 512         // targets per bucket
#define EPA 8            // edges per thread in A0/A
#define ACHUNK (EPA * TPB)

typedef _Float16 f16x8 __attribute__((ext_vector_type(8)));
typedef float    f32x4 __attribute__((ext_vector_type(4)));

// ---------------------------------------------------------------------------
// Convert x (fp32->fp16) and the 4 weight matrices (8192 elems each) into ws.
// Pair-granular so no float2 crosses an array boundary.
// ---------------------------------------------------------------------------
__global__ __launch_bounds__(256) void convert_kernel(
        const float* __restrict__ x,
        const float* __restrict__ W1p, const float* __restrict__ W1n,
        const float* __restrict__ W2p, const float* __restrict__ W2n,
        __half* __restrict__ x16, __half* __restrict__ w16, int nx) {
    int p = blockIdx.x * blockDim.x + threadIdx.x;   // pair index
    int npx = nx >> 1;
    if (p < npx) {
        float2 v = *(const float2*)(x + 2 * (size_t)p);
        ((__half2*)x16)[p] = __floats2half2_rn(v.x, v.y);
    } else {
        int q = p - npx;                              // weight pair index
        if (q < 16384) {
            const float* Wsrc = (q < 4096) ? W1p : (q < 8192) ? W1n
                              : (q < 12288) ? W2p : W2n;
            int off = (q & 4095) * 2;
            float2 v = *(const float2*)(Wsrc + off);
            ((__half2*)w16)[q] = __floats2half2_rn(v.x, v.y);
        }
    }
}

// ---------------------------------------------------------------------------
// A0: per-bucket edge counts (LDS-aggregated, padded global atomics).
// ---------------------------------------------------------------------------
__global__ __launch_bounds__(256) void bucket_count_kernel(
        const int* __restrict__ tgt, int* __restrict__ cnt_pad, int E) {
    __shared__ int lcnt[256];
    const int tid = threadIdx.x;
    lcnt[tid] = 0;
    __syncthreads();
    const int base = blockIdx.x * ACHUNK + tid;
#pragma unroll
    for (int j = 0; j < EPA; ++j) {
        int e = base + j * TPB;
        if (e < E) atomicAdd(&lcnt[tgt[e] >> BSH], 1);
    }
    __syncthreads();
    if (lcnt[tid]) atomicAdd(&cnt_pad[tid * 16], lcnt[tid]);
}

// ---------------------------------------------------------------------------
// scanTot: exclusive scan of bucket totals; init padded pass-A cursors.
// ---------------------------------------------------------------------------
__global__ __launch_bounds__(256) void bucket_scan_kernel(
        const int* __restrict__ cnt_pad, int* __restrict__ bucket_start,
        int* __restrict__ cursor_pad, int nb, int E) {
    __shared__ int sm[256];
    const int tid = threadIdx.x;
    int v = (tid < nb) ? cnt_pad[tid * 16] : 0;
    const int orig = v;
    sm[tid] = v;
    __syncthreads();
#pragma unroll
    for (int off = 1; off < 256; off <<= 1) {
        int add = (tid >= off) ? sm[tid - off] : 0;
        __syncthreads();
        sm[tid] += add;
        __syncthreads();
    }
    int excl = sm[tid] - orig;
    if (tid < nb) {
        bucket_start[tid] = excl;
        cursor_pad[tid * 16] = excl;
    }
    if (tid == 0) bucket_start[nb] = E;
}

// ---------------------------------------------------------------------------
// A: bucket scatter. rec (int2) = {(t_local<<23)|(src<<6)|flag, bitcast(w)}
// (t_local 9b, src 17b, flag 1b). Halves R11's int4 write volume.
// ---------------------------------------------------------------------------
__global__ __launch_bounds__(256) void bucket_scatter_kernel(
        const int* __restrict__ tgt, const int* __restrict__ src,
        const float* __restrict__ ew, int* __restrict__ cursor_pad,
        int2* __restrict__ recs, int E) {
    __shared__ int lcnt[256];
    __shared__ int lbase[256];
    const int tid = threadIdx.x;
    lcnt[tid] = 0;
    __syncthreads();
    const int base = blockIdx.x * ACHUNK + tid;
    int px[EPA], pw[EPA], mr[EPA], mb[EPA];
#pragma unroll
    for (int j = 0; j < EPA; ++j) {
        int e = base + j * TPB;
        if (e < E) {
            int t = tgt[e], s = src[e];
            float w = ew[e];
            int flag = (w < 0.0f) ? 1 : 0;
            mb[j] = t >> BSH;
            px[j] = ((t & (BTGT - 1)) << 23) | (s << 6) | flag;
            pw[j] = __float_as_int(w);
            mr[j] = atomicAdd(&lcnt[mb[j]], 1);
        }
    }
    __syncthreads();
    if (lcnt[tid]) lbase[tid] = atomicAdd(&cursor_pad[tid * 16], lcnt[tid]);
    __syncthreads();
#pragma unroll
    for (int j = 0; j < EPA; ++j) {
        int e = base + j * TPB;
        if (e < E) recs[lbase[mb[j]] + mr[j]] = make_int2(px[j], pw[j]);
    }
}

// ---------------------------------------------------------------------------
// B: per-bucket CSR build + FUSED degrees/dinv/norm-fold (deg_dinv kernel
// deleted). Pass 1: LDS hist + LDS float degree atomics. Scan, rowstart,
// dinv (kept in LDS). Pass 2: ranked placement writing edat with
// pre-normalized .y = w * dinv_sign[t].
// ---------------------------------------------------------------------------
__global__ __launch_bounds__(256) void csr_build_kernel(
        const int* __restrict__ bucket_start, const int2* __restrict__ recs,
        int* __restrict__ rowstart, int2* __restrict__ edat,
        float* __restrict__ dinvp, float* __restrict__ dinvn,
        int n, int nb, int E) {
    __shared__ int   hcnt[BTGT];
    __shared__ int   cur[BTGT];
    __shared__ int   sm[256];
    __shared__ float sdp[BTGT];
    __shared__ float sdn[BTGT];
    const int b = blockIdx.x, tid = threadIdx.x;
    const int beg = bucket_start[b], end = bucket_start[b + 1];
    hcnt[tid] = 0; hcnt[tid + 256] = 0;
    sdp[tid] = 0.f; sdp[tid + 256] = 0.f;
    sdn[tid] = 0.f; sdn[tid + 256] = 0.f;
    __syncthreads();
    for (int i = beg + tid; i < end; i += 256) {
        int2 r = recs[i];
        int tl = ((unsigned)r.x) >> 23;
        atomicAdd(&hcnt[tl], 1);
        float w = __int_as_float(r.y);
        if (w > 0.0f)      atomicAdd(&sdp[tl], w);
        else if (w < 0.0f) atomicAdd(&sdn[tl], -w);
    }
    __syncthreads();
    // exclusive scan of 512 via 256-thread pair scan
    int pairsum = hcnt[2 * tid] + hcnt[2 * tid + 1];
    sm[tid] = pairsum;
    __syncthreads();
#pragma unroll
    for (int off = 1; off < 256; off <<= 1) {
        int add = (tid >= off) ? sm[tid - off] : 0;
        __syncthreads();
        sm[tid] += add;
        __syncthreads();
    }
    int epair = sm[tid] - pairsum;
    cur[2 * tid]     = epair;
    cur[2 * tid + 1] = epair + hcnt[2 * tid];
    __syncthreads();
    const int t0 = b << BSH;
#pragma unroll
    for (int jj = 0; jj < 2; ++jj) {
        int j = tid + jj * 256;
        int t = t0 + j;
        if (t < n) {
            rowstart[t] = beg + cur[j];
            float dp = rsqrtf(sdp[j] + 1.0f);
            float dn = rsqrtf(sdn[j] + 1.0f);
            dinvp[t] = dp; dinvn[t] = dn;
            sdp[j] = dp; sdn[j] = dn;
        }
    }
    if (b == nb - 1 && tid == 0) rowstart[n] = E;
    __syncthreads();
    for (int i = beg + tid; i < end; i += 256) {
        int2 r = recs[i];
        int tl = ((unsigned)r.x) >> 23;
        int rank = atomicAdd(&cur[tl], 1);
        float w = __int_as_float(r.y);
        float nv = w * ((r.x & 1) ? sdn[tl] : sdp[tl]);
        int srcflag = (((r.x >> 6) & 0x1FFFF) << 8) | (r.x & 1);
        edat[beg + rank] = make_int2(srcflag, __float_as_int(nv));
    }
}

// ---------------------------------------------------------------------------
// MFMA GEMM layer 1: hp/hn[row][128] = half( (x16 @ W^T) * dinv[row] ).
// Wave = 16 rows x 128 cols, K=64, no LDS. Layouts (m89/m91-verified):
// A: m=lane&15, k=quad*8+j; B: n=lane&15, k=quad*8+j; C/D: col=lane&15,
// row=quad*4+reg.
// ---------------------------------------------------------------------------
__global__ __launch_bounds__(256) void gemm1_mfma(
        const __half* __restrict__ x16,
        const __half* __restrict__ wp, const __half* __restrict__ wn,
        const float* __restrict__ dinvp, const float* __restrict__ dinvn,
        __half* __restrict__ hp, __half* __restrict__ hn, int n) {
    const int lane = threadIdx.x & 63;
    const int wv = threadIdx.x >> 6;
    const int m = lane & 15, quad = lane >> 4;
    const int row0 = (blockIdx.x * 4 + wv) * 16;
    if (row0 >= n) return;
    const __half* W    = blockIdx.y ? wn : wp;
    const float*  dinv = blockIdx.y ? dinvn : dinvp;
    __half*       dst  = blockIdx.y ? hn : hp;
    int arow = row0 + m; if (arow > n - 1) arow = n - 1;
    f32x4 acc[8];
#pragma unroll
    for (int t = 0; t < 8; ++t) acc[t] = (f32x4){0.f, 0.f, 0.f, 0.f};
#pragma unroll
    for (int kc = 0; kc < 2; ++kc) {
        f16x8 a = *(const f16x8*)(x16 + (size_t)arow * 64 + kc * 32 + quad * 8);
#pragma unroll
        for (int t = 0; t < 8; ++t) {
            f16x8 bfr = *(const f16x8*)(W + (size_t)(t * 16 + m) * 64 + kc * 32 + quad * 8);
            acc[t] = __builtin_amdgcn_mfma_f32_16x16x32_f16(a, bfr, acc[t], 0, 0, 0);
        }
    }
    float sc[4]; int rows[4];
#pragma unroll
    for (int r = 0; r < 4; ++r) {
        int rw = row0 + quad * 4 + r;
        rows[r] = rw;
        sc[r] = (rw < n) ? dinv[rw] : 0.f;
    }
#pragma unroll
    for (int t = 0; t < 8; ++t)
#pragma unroll
        for (int r = 0; r < 4; ++r)
            if (rows[r] < n)
                dst[(size_t)rows[r] * 128 + t * 16 + m] = (__half)(acc[t][r] * sc[r]);
}

// ---------------------------------------------------------------------------
// MFMA GEMM layer 2 (dual): K=128; tiles 0-3 -> w2p -> hp2, 4-7 -> w2n -> hn2.
// ---------------------------------------------------------------------------
__global__ __launch_bounds__(256) void gemm2_mfma(
        const __half* __restrict__ h16,
        const __half* __restrict__ wp, const __half* __restrict__ wn,
        const float* __restrict__ dinvp, const float* __restrict__ dinvn,
        __half* __restrict__ hp2, __half* __restrict__ hn2, int n) {
    const int lane = threadIdx.x & 63;
    const int wv = threadIdx.x >> 6;
    const int m = lane & 15, quad = lane >> 4;
    const int row0 = (blockIdx.x * 4 + wv) * 16;
    if (row0 >= n) return;
    int arow = row0 + m; if (arow > n - 1) arow = n - 1;
    f32x4 acc[8];
#pragma unroll
    for (int t = 0; t < 8; ++t) acc[t] = (f32x4){0.f, 0.f, 0.f, 0.f};
#pragma unroll
    for (int kc = 0; kc < 4; ++kc) {
        f16x8 a = *(const f16x8*)(h16 + (size_t)arow * 128 + kc * 32 + quad * 8);
#pragma unroll
        for (int t = 0; t < 8; ++t) {
            const __half* W = (t < 4) ? wp : wn;
            f16x8 bfr = *(const f16x8*)(W + (size_t)((t & 3) * 16 + m) * 128 + kc * 32 + quad * 8);
            acc[t] = __builtin_amdgcn_mfma_f32_16x16x32_f16(a, bfr, acc[t], 0, 0, 0);
        }
    }
    float sp[4], sn[4]; int rows[4];
#pragma unroll
    for (int r = 0; r < 4; ++r) {
        int rw = row0 + quad * 4 + r;
        rows[r] = rw;
        sp[r] = (rw < n) ? dinvp[rw] : 0.f;
        sn[r] = (rw < n) ? dinvn[rw] : 0.f;
    }
#pragma unroll
    for (int t = 0; t < 8; ++t) {
        __half* dst = (t < 4) ? hp2 : hn2;
        int col = (t & 3) * 16 + m;
#pragma unroll
        for (int r = 0; r < 4; ++r)
            if (rows[r] < n) {
                float s = (t < 4) ? sp[r] : sn[r];
                dst[(size_t)rows[r] * 64 + col] = (__half)(acc[t][r] * s);
            }
    }
}

// ---------------------------------------------------------------------------
// Gather, F=128: one wave per target, wave-uniform scalar edge stream,
// norm pre-folded in edat.y, byte offset in edat.x, unroll x4. OUT fp16.
// ---------------------------------------------------------------------------
__global__ __launch_bounds__(256) void gather128_kernel(
        const int* __restrict__ rowstart, const int2* __restrict__ edat,
        const __half* __restrict__ hp, const __half* __restrict__ hn,
        const float* __restrict__ dinvp, const float* __restrict__ dinvn,
        const float* __restrict__ bp, const float* __restrict__ bn,
        __half* __restrict__ out, int n) {
    const int lane = threadIdx.x & 63;
    int t = (blockIdx.x * blockDim.x + threadIdx.x) >> 6;
    if (t >= n) return;
    t = __builtin_amdgcn_readfirstlane(t);
    const char* hpB = (const char*)hp;
    const char* hnB = (const char*)hn;
    int beg = rowstart[t], end = rowstart[t + 1];
    float2 acc0 = {0.f, 0.f}, acc1 = {0.f, 0.f};
    float2 acc2 = {0.f, 0.f}, acc3 = {0.f, 0.f};
    int e = beg;
    for (; e + 3 < end; e += 4) {
        int2 d0 = edat[e], d1 = edat[e + 1], d2 = edat[e + 2], d3 = edat[e + 3];
        const __half2* r0 = (const __half2*)(((d0.x & 1) ? hnB : hpB) + (d0.x & 0xFFFFFF00u));
        const __half2* r1 = (const __half2*)(((d1.x & 1) ? hnB : hpB) + (d1.x & 0xFFFFFF00u));
        const __half2* r2 = (const __half2*)(((d2.x & 1) ? hnB : hpB) + (d2.x & 0xFFFFFF00u));
        const __half2* r3 = (const __half2*)(((d3.x & 1) ? hnB : hpB) + (d3.x & 0xFFFFFF00u));
        float2 v0 = __half22float2(r0[lane]);
        float2 v1 = __half22float2(r1[lane]);
        float2 v2 = __half22float2(r2[lane]);
        float2 v3 = __half22float2(r3[lane]);
        float nv0 = __int_as_float(d0.y), nv1 = __int_as_float(d1.y);
        float nv2 = __int_as_float(d2.y), nv3 = __int_as_float(d3.y);
        acc0.x += v0.x * nv0; acc0.y += v0.y * nv0;
        acc1.x += v1.x * nv1; acc1.y += v1.y * nv1;
        acc2.x += v2.x * nv2; acc2.y += v2.y * nv2;
        acc3.x += v3.x * nv3; acc3.y += v3.y * nv3;
    }
    for (; e < end; ++e) {
        int2 d0 = edat[e];
        const __half2* r0 = (const __half2*)(((d0.x & 1) ? hnB : hpB) + (d0.x & 0xFFFFFF00u));
        float2 v0 = __half22float2(r0[lane]);
        float nv0 = __int_as_float(d0.y);
        acc0.x += v0.x * nv0; acc0.y += v0.y * nv0;
    }
    const float dp = dinvp[t], dn = dinvn[t];
    const __half2* hp2 = (const __half2*)hp;
    const __half2* hn2 = (const __half2*)hn;
    float2 hpv = __half22float2(hp2[(size_t)t * 64 + lane]);
    float2 hnv = __half22float2(hn2[(size_t)t * 64 + lane]);
    float o0 = acc0.x + acc1.x + acc2.x + acc3.x + hpv.x * dp + bp[2*lane]   - hnv.x * dn - bn[2*lane];
    float o1 = acc0.y + acc1.y + acc2.y + acc3.y + hpv.y * dp + bp[2*lane+1] - hnv.y * dn - bn[2*lane+1];
    __half2 r = __floats2half2_rn(fmaxf(o0, 0.f), fmaxf(o1, 0.f));
    *(__half2*)(out + ((size_t)t << 7) + 2 * lane) = r;
}

// Gather, F=64 (fp16 rows 128 B: offset = (edat.x & ~255) >> 1). fp32 out.
__global__ __launch_bounds__(256) void gather64_kernel(
        const int* __restrict__ rowstart, const int2* __restrict__ edat,
        const __half* __restrict__ hp, const __half* __restrict__ hn,
        const float* __restrict__ dinvp, const float* __restrict__ dinvn,
        const float* __restrict__ bp, const float* __restrict__ bn,
        float* __restrict__ out, int n) {
    const int lane = threadIdx.x & 63;
    int t = (blockIdx.x * blockDim.x + threadIdx.x) >> 6;
    if (t >= n) return;
    t = __builtin_amdgcn_readfirstlane(t);
    const char* hpB = (const char*)hp;
    const char* hnB = (const char*)hn;
    int beg = rowstart[t], end = rowstart[t + 1];
    float acc0 = 0.f, acc1 = 0.f, acc2 = 0.f, acc3 = 0.f;
    int e = beg;
    for (; e + 3 < end; e += 4) {
        int2 d0 = edat[e], d1 = edat[e + 1], d2 = edat[e + 2], d3 = edat[e + 3];
        const __half* r0 = (const __half*)(((d0.x & 1) ? hnB : hpB) + ((d0.x & 0xFFFFFF00u) >> 1));
        const __half* r1 = (const __half*)(((d1.x & 1) ? hnB : hpB) + ((d1.x & 0xFFFFFF00u) >> 1));
        const __half* r2 = (const __half*)(((d2.x & 1) ? hnB : hpB) + ((d2.x & 0xFFFFFF00u) >> 1));
        const __half* r3 = (const __half*)(((d3.x & 1) ? hnB : hpB) + ((d3.x & 0xFFFFFF00u) >> 1));
        float v0 = __half2float(r0[lane]);
        float v1 = __half2float(r1[lane]);
        float v2 = __half2float(r2[lane]);
        float v3 = __half2float(r3[lane]);
        acc0 += v0 * __int_as_float(d0.y);
        acc1 += v1 * __int_as_float(d1.y);
        acc2 += v2 * __int_as_float(d2.y);
        acc3 += v3 * __int_as_float(d3.y);
    }
    for (; e < end; ++e) {
        int2 d0 = edat[e];
        const __half* r0 = (const __half*)(((d0.x & 1) ? hnB : hpB) + ((d0.x & 0xFFFFFF00u) >> 1));
        acc0 += __half2float(r0[lane]) * __int_as_float(d0.y);
    }
    const float dp = dinvp[t], dn = dinvn[t];
    float hpv = __half2float(hp[(size_t)t * 64 + lane]);
    float hnv = __half2float(hn[(size_t)t * 64 + lane]);
    float o = acc0 + acc1 + acc2 + acc3 + hpv * dp + bp[lane] - hnv * dn - bn[lane];
    out[(size_t)t * 64 + lane] = fmaxf(o, 0.f);
}

// ---------------------------------------------------------------------------
extern "C" void kernel_launch(void* const* d_in, const int* in_sizes, int n_in,
                              void* d_out, int out_size, void* d_ws, size_t ws_size,
                              hipStream_t stream) {
    const float* x   = (const float*)d_in[0];
    const int*   ei  = (const int*)d_in[1];
    const float* ew  = (const float*)d_in[2];
    const float* W1p = (const float*)d_in[3];
    const float* b1p = (const float*)d_in[4];
    const float* W1n = (const float*)d_in[5];
    const float* b1n = (const float*)d_in[6];
    const float* W2p = (const float*)d_in[7];
    const float* b2p = (const float*)d_in[8];
    const float* W2n = (const float*)d_in[9];
    const float* b2n = (const float*)d_in[10];

    const int E = in_sizes[2];
    const int n = in_sizes[0] / 64;  // IN = 64
    const int nb = (n + BTGT - 1) >> BSH;
    const int nx = n * 64;
    const int* src = ei;
    const int* tgt = ei + E;

    // ws layout (4B units): cnt_pad[4096] | cursor_pad[4096] | bucket_start[257]
    //   | (pad) dinvp[n] | dinvn[n] | rowstart[n+1] | (pad16) x16[nx]h |
    //   w16[32768]h | recs[E]int2 | edat[E]int2 | hp1[128n]h | hn1[128n]h |
    //   h[128n]h.  layer2: hp2/hn2 reuse hp1.  ~117 MB.
    int* wsi          = (int*)d_ws;
    int* cnt_pad      = wsi;
    int* cursor_pad   = wsi + 4096;
    int* bucket_start = wsi + 8192;
    size_t o = 8452;                                  // 16B-aligned
    float* dinvp    = (float*)(wsi + o);  o += n;
    float* dinvn    = (float*)(wsi + o);  o += n;
    int*   rowstart = (int*)(wsi + o);    o += n + 1;
    o = (o + 3) & ~(size_t)3;
    __half* x16 = (__half*)(wsi + o);     o += (size_t)nx / 2;
    __half* w16 = (__half*)(wsi + o);     o += 16384;
    __half* w1p16 = w16, *w1n16 = w16 + 8192, *w2p16 = w16 + 16384, *w2n16 = w16 + 24576;
    int2* recs = (int2*)(wsi + o);        o += 2 * (size_t)E;
    int2* edat = (int2*)(wsi + o);        o += 2 * (size_t)E;
    __half* hp1 = (__half*)(wsi + o);     o += (size_t)n * 64;
    __half* hn1 = (__half*)(wsi + o);     o += (size_t)n * 64;
    __half* h   = (__half*)(wsi + o);
    __half* hp2 = hp1;
    __half* hn2 = hp1 + (size_t)n * 64;
    float*  out = (float*)d_out;

    hipMemsetAsync(cnt_pad, 0, 4096 * sizeof(int), stream);

    const int gridCv = (nx / 2 + 16384 + TPB - 1) / TPB;
    const int gridA  = (E + ACHUNK - 1) / ACHUNK;
    const int gridW  = (n * 64 + TPB - 1) / TPB;
    const int gridG  = (n + 63) / 64;     // 64 rows per block (4 waves x 16)

    convert_kernel<<<gridCv, TPB, 0, stream>>>(x, W1p, W1n, W2p, W2n, x16, w16, nx);
    bucket_count_kernel<<<gridA, TPB, 0, stream>>>(tgt, cnt_pad, E);
    bucket_scan_kernel<<<1, TPB, 0, stream>>>(cnt_pad, bucket_start, cursor_pad, nb, E);
    bucket_scatter_kernel<<<gridA, TPB, 0, stream>>>(tgt, src, ew, cursor_pad, recs, E);
    csr_build_kernel<<<nb, TPB, 0, stream>>>(bucket_start, recs, rowstart, edat,
                                             dinvp, dinvn, n, nb, E);

    // ---- layer 1: IN=64 -> H=128 (MFMA) ----
    gemm1_mfma<<<dim3(gridG, 2), TPB, 0, stream>>>(x16, w1p16, w1n16, dinvp, dinvn,
                                                   hp1, hn1, n);
    gather128_kernel<<<gridW, TPB, 0, stream>>>(rowstart, edat, hp1, hn1, dinvp, dinvn,
                                                b1p, b1n, h, n);

    // ---- layer 2: H=128 -> OUT=64 (MFMA, dual) ----
    gemm2_mfma<<<gridG, TPB, 0, stream>>>(h, w2p16, w2n16, dinvp, dinvn, hp2, hn2, n);
    gather64_kernel<<<gridW, TPB, 0, stream>>>(rowstart, edat, hp2, hn2, dinvp, dinvn,
                                               b2p, b2n, out, n);
}

// Round 13
// 382.135 us; speedup vs baseline: 1.5095x; 1.0889x over previous
//
#include <hip/hip_runtime.h>
#include <hip/hip_fp16.h>
#include <cstddef>

#define TPB 256
#define BSH 9            // log2(targets per bucket)
#define BTGT 512         // targets per bucket
#define EPA 8            // edges per thread in A0/A
#define ACHUNK (EPA * TPB)

typedef _Float16 f16x8 __attribute__((ext_vector_type(8)));
typedef float    f32x4 __attribute__((ext_vector_type(4)));

// ---------------------------------------------------------------------------
// A0: per-bucket edge counts (LDS-aggregated, padded global atomics).
// ---------------------------------------------------------------------------
__global__ __launch_bounds__(256) void bucket_count_kernel(
        const int* __restrict__ tgt, int* __restrict__ cnt_pad, int E) {
    __shared__ int lcnt[256];
    const int tid = threadIdx.x;
    lcnt[tid] = 0;
    __syncthreads();
    const int base = blockIdx.x * ACHUNK + tid;
#pragma unroll
    for (int j = 0; j < EPA; ++j) {
        int e = base + j * TPB;
        if (e < E) atomicAdd(&lcnt[tgt[e] >> BSH], 1);
    }
    __syncthreads();
    if (lcnt[tid]) atomicAdd(&cnt_pad[tid * 16], lcnt[tid]);
}

// ---------------------------------------------------------------------------
// scanTot: exclusive scan of bucket totals; init padded pass-A cursors.
// ---------------------------------------------------------------------------
__global__ __launch_bounds__(256) void bucket_scan_kernel(
        const int* __restrict__ cnt_pad, int* __restrict__ bucket_start,
        int* __restrict__ cursor_pad, int nb, int E) {
    __shared__ int sm[256];
    const int tid = threadIdx.x;
    int v = (tid < nb) ? cnt_pad[tid * 16] : 0;
    const int orig = v;
    sm[tid] = v;
    __syncthreads();
#pragma unroll
    for (int off = 1; off < 256; off <<= 1) {
        int add = (tid >= off) ? sm[tid - off] : 0;
        __syncthreads();
        sm[tid] += add;
        __syncthreads();
    }
    int excl = sm[tid] - orig;
    if (tid < nb) {
        bucket_start[tid] = excl;
        cursor_pad[tid * 16] = excl;
    }
    if (tid == 0) bucket_start[nb] = E;
}

// ---------------------------------------------------------------------------
// A: bucket scatter. rec (int2) = {(t_local<<23)|(src<<6)|flag, bitcast(w)}.
// ---------------------------------------------------------------------------
__global__ __launch_bounds__(256) void bucket_scatter_kernel(
        const int* __restrict__ tgt, const int* __restrict__ src,
        const float* __restrict__ ew, int* __restrict__ cursor_pad,
        int2* __restrict__ recs, int E) {
    __shared__ int lcnt[256];
    __shared__ int lbase[256];
    const int tid = threadIdx.x;
    lcnt[tid] = 0;
    __syncthreads();
    const int base = blockIdx.x * ACHUNK + tid;
    int px[EPA], pw[EPA], mr[EPA], mb[EPA];
#pragma unroll
    for (int j = 0; j < EPA; ++j) {
        int e = base + j * TPB;
        if (e < E) {
            int t = tgt[e], s = src[e];
            float w = ew[e];
            int flag = (w < 0.0f) ? 1 : 0;
            mb[j] = t >> BSH;
            px[j] = ((t & (BTGT - 1)) << 23) | (s << 6) | flag;
            pw[j] = __float_as_int(w);
            mr[j] = atomicAdd(&lcnt[mb[j]], 1);
        }
    }
    __syncthreads();
    if (lcnt[tid]) lbase[tid] = atomicAdd(&cursor_pad[tid * 16], lcnt[tid]);
    __syncthreads();
#pragma unroll
    for (int j = 0; j < EPA; ++j) {
        int e = base + j * TPB;
        if (e < E) recs[lbase[mb[j]] + mr[j]] = make_int2(px[j], pw[j]);
    }
}

// ---------------------------------------------------------------------------
// B: per-bucket CSR build + fused degrees/dinv/norm-fold.
// edat[slot] = {(src<<8)|(flag<<7)|flag, bitcast(w * dinv_sign[t])}.
// (src<<8)|(flag<<7) is the byte offset of the selected 128 B half-row in a
// 256 B combined row — used by BOTH gathers with a single AND.
// ---------------------------------------------------------------------------
__global__ __launch_bounds__(256) void csr_build_kernel(
        const int* __restrict__ bucket_start, const int2* __restrict__ recs,
        int* __restrict__ rowstart, int2* __restrict__ edat,
        float* __restrict__ dinvp, float* __restrict__ dinvn,
        int n, int nb, int E) {
    __shared__ int   hcnt[BTGT];
    __shared__ int   cur[BTGT];
    __shared__ int   sm[256];
    __shared__ float sdp[BTGT];
    __shared__ float sdn[BTGT];
    const int b = blockIdx.x, tid = threadIdx.x;
    const int beg = bucket_start[b], end = bucket_start[b + 1];
    hcnt[tid] = 0; hcnt[tid + 256] = 0;
    sdp[tid] = 0.f; sdp[tid + 256] = 0.f;
    sdn[tid] = 0.f; sdn[tid + 256] = 0.f;
    __syncthreads();
    for (int i = beg + tid; i < end; i += 256) {
        int2 r = recs[i];
        int tl = ((unsigned)r.x) >> 23;
        atomicAdd(&hcnt[tl], 1);
        float w = __int_as_float(r.y);
        if (w > 0.0f)      atomicAdd(&sdp[tl], w);
        else if (w < 0.0f) atomicAdd(&sdn[tl], -w);
    }
    __syncthreads();
    int pairsum = hcnt[2 * tid] + hcnt[2 * tid + 1];
    sm[tid] = pairsum;
    __syncthreads();
#pragma unroll
    for (int off = 1; off < 256; off <<= 1) {
        int add = (tid >= off) ? sm[tid - off] : 0;
        __syncthreads();
        sm[tid] += add;
        __syncthreads();
    }
    int epair = sm[tid] - pairsum;
    cur[2 * tid]     = epair;
    cur[2 * tid + 1] = epair + hcnt[2 * tid];
    __syncthreads();
    const int t0 = b << BSH;
#pragma unroll
    for (int jj = 0; jj < 2; ++jj) {
        int j = tid + jj * 256;
        int t = t0 + j;
        if (t < n) {
            rowstart[t] = beg + cur[j];
            float dp = rsqrtf(sdp[j] + 1.0f);
            float dn = rsqrtf(sdn[j] + 1.0f);
            dinvp[t] = dp; dinvn[t] = dn;
            sdp[j] = dp; sdn[j] = dn;
        }
    }
    if (b == nb - 1 && tid == 0) rowstart[n] = E;
    __syncthreads();
    for (int i = beg + tid; i < end; i += 256) {
        int2 r = recs[i];
        int tl = ((unsigned)r.x) >> 23;
        int rank = atomicAdd(&cur[tl], 1);
        float w = __int_as_float(r.y);
        int flag = r.x & 1;
        float nv = w * (flag ? sdn[tl] : sdp[tl]);
        int srcflag = (((r.x >> 6) & 0x1FFFF) << 8) | (flag << 7) | flag;
        edat[beg + rank] = make_int2(srcflag, __float_as_int(nv));
    }
}

// ---------------------------------------------------------------------------
// Convert (after csr_build): xs[row] = [x*dinvp | x*dinvn] (fp16, 256 B/row)
// and the 4 weight matrices to fp16.
// ---------------------------------------------------------------------------
__global__ __launch_bounds__(256) void convert_kernel(
        const float* __restrict__ x,
        const float* __restrict__ dinvp, const float* __restrict__ dinvn,
        const float* __restrict__ W1p, const float* __restrict__ W1n,
        const float* __restrict__ W2p, const float* __restrict__ W2n,
        __half* __restrict__ xs, __half* __restrict__ w16, int n) {
    int idx = blockIdx.x * blockDim.x + threadIdx.x;
    int npx = n * 32;               // feature-pairs of x
    if (idx < npx) {
        int row = idx >> 5, jp = idx & 31;
        float2 v = *(const float2*)(x + (size_t)row * 64 + jp * 2);
        float dp = dinvp[row], dn = dinvn[row];
        __half2* xr = (__half2*)(xs + (size_t)row * 128);
        xr[jp]      = __floats2half2_rn(v.x * dp, v.y * dp);
        xr[jp + 32] = __floats2half2_rn(v.x * dn, v.y * dn);
    } else {
        int q = idx - npx;
        if (q < 16384) {
            const float* Wsrc = (q < 4096) ? W1p : (q < 8192) ? W1n
                              : (q < 12288) ? W2p : W2n;
            float2 v = *(const float2*)(Wsrc + (q & 4095) * 2);
            ((__half2*)w16)[q] = __floats2half2_rn(v.x, v.y);
        }
    }
}

// ---------------------------------------------------------------------------
// gatherX: layer-1 aggregation in 64-dim x-space (128 B/edge — half of the
// old h-space gather). agg[row] = [aggP | aggNs] (fp16, 256 B/row):
//   aggP  = sum_pos nv*(x*dinvp)[src] + dinvp[t]*xp[t]
//   aggNs = sum_neg nv*(x*dinvn)[src] - dinvn[t]*xn[t]   (nv<0 for neg)
// ---------------------------------------------------------------------------
__global__ __launch_bounds__(256) void gatherX_kernel(
        const int* __restrict__ rowstart, const int2* __restrict__ edat,
        const __half* __restrict__ xs,
        const float* __restrict__ dinvp, const float* __restrict__ dinvn,
        __half* __restrict__ agg, int n) {
    const int lane = threadIdx.x & 63;
    int t = (blockIdx.x * blockDim.x + threadIdx.x) >> 6;
    if (t >= n) return;
    t = __builtin_amdgcn_readfirstlane(t);
    const char* xB = (const char*)xs;
    int beg = rowstart[t], end = rowstart[t + 1];
    float aP0 = 0.f, aP1 = 0.f, aP2 = 0.f, aP3 = 0.f;
    float aN0 = 0.f, aN1 = 0.f, aN2 = 0.f, aN3 = 0.f;
    int e = beg;
    for (; e + 3 < end; e += 4) {
        int2 d0 = edat[e], d1 = edat[e + 1], d2 = edat[e + 2], d3 = edat[e + 3];
        const __half* r0 = (const __half*)(xB + (d0.x & 0xFFFFFF80u));
        const __half* r1 = (const __half*)(xB + (d1.x & 0xFFFFFF80u));
        const __half* r2 = (const __half*)(xB + (d2.x & 0xFFFFFF80u));
        const __half* r3 = (const __half*)(xB + (d3.x & 0xFFFFFF80u));
        float c0 = __half2float(r0[lane]) * __int_as_float(d0.y);
        float c1 = __half2float(r1[lane]) * __int_as_float(d1.y);
        float c2 = __half2float(r2[lane]) * __int_as_float(d2.y);
        float c3 = __half2float(r3[lane]) * __int_as_float(d3.y);
        if (d0.x & 1) aN0 += c0; else aP0 += c0;
        if (d1.x & 1) aN1 += c1; else aP1 += c1;
        if (d2.x & 1) aN2 += c2; else aP2 += c2;
        if (d3.x & 1) aN3 += c3; else aP3 += c3;
    }
    for (; e < end; ++e) {
        int2 d0 = edat[e];
        const __half* r0 = (const __half*)(xB + (d0.x & 0xFFFFFF80u));
        float c0 = __half2float(r0[lane]) * __int_as_float(d0.y);
        if (d0.x & 1) aN0 += c0; else aP0 += c0;
    }
    float sp = dinvp[t], sn = dinvn[t];
    float accP = aP0 + aP1 + aP2 + aP3 + sp * __half2float(xs[(size_t)t * 128 + lane]);
    float accN = aN0 + aN1 + aN2 + aN3 - sn * __half2float(xs[(size_t)t * 128 + 64 + lane]);
    agg[(size_t)t * 128 + lane]      = (__half)accP;
    agg[(size_t)t * 128 + 64 + lane] = (__half)accN;
}

// ---------------------------------------------------------------------------
// Fused MFMA layer-1 GEMM: h = relu([aggP|aggNs] @ [W1p|W1n]^T + (b1p-b1n)).
// Wave = 16 rows x 128 cols, K=128. Layouts m89/m91-verified.
// ---------------------------------------------------------------------------
__global__ __launch_bounds__(256) void gemm1_mfma(
        const __half* __restrict__ agg,
        const __half* __restrict__ w1p, const __half* __restrict__ w1n,
        const float* __restrict__ b1p, const float* __restrict__ b1n,
        __half* __restrict__ h, int n) {
    const int lane = threadIdx.x & 63;
    const int wv = threadIdx.x >> 6;
    const int m = lane & 15, quad = lane >> 4;
    const int row0 = (blockIdx.x * 4 + wv) * 16;
    if (row0 >= n) return;
    int arow = row0 + m; if (arow > n - 1) arow = n - 1;
    f32x4 acc[8];
#pragma unroll
    for (int t = 0; t < 8; ++t) acc[t] = (f32x4){0.f, 0.f, 0.f, 0.f};
#pragma unroll
    for (int kc = 0; kc < 4; ++kc) {
        f16x8 a = *(const f16x8*)(agg + (size_t)arow * 128 + kc * 32 + quad * 8);
        const __half* W = (kc < 2) ? w1p : w1n;
        const int ko = (kc & 1) * 32 + quad * 8;
#pragma unroll
        for (int t = 0; t < 8; ++t) {
            f16x8 bfr = *(const f16x8*)(W + (size_t)(t * 16 + m) * 64 + ko);
            acc[t] = __builtin_amdgcn_mfma_f32_16x16x32_f16(a, bfr, acc[t], 0, 0, 0);
        }
    }
    int rows[4];
#pragma unroll
    for (int r = 0; r < 4; ++r) rows[r] = row0 + quad * 4 + r;
#pragma unroll
    for (int t = 0; t < 8; ++t) {
        int col = t * 16 + m;
        float bd = b1p[col] - b1n[col];
#pragma unroll
        for (int r = 0; r < 4; ++r)
            if (rows[r] < n)
                h[(size_t)rows[r] * 128 + col] = (__half)fmaxf(acc[t][r] + bd, 0.f);
    }
}

// ---------------------------------------------------------------------------
// MFMA GEMM layer 2 (dual): K=128; writes combined g2[row] = [hp2|hn2]
// (256 B rows, matching the gather offset trick). Tiles 0-3 use W2p*dinvp
// (cols 0-63), 4-7 use W2n*dinvn (cols 64-127).
// ---------------------------------------------------------------------------
__global__ __launch_bounds__(256) void gemm2_mfma(
        const __half* __restrict__ h16,
        const __half* __restrict__ wp, const __half* __restrict__ wn,
        const float* __restrict__ dinvp, const float* __restrict__ dinvn,
        __half* __restrict__ g2, int n) {
    const int lane = threadIdx.x & 63;
    const int wv = threadIdx.x >> 6;
    const int m = lane & 15, quad = lane >> 4;
    const int row0 = (blockIdx.x * 4 + wv) * 16;
    if (row0 >= n) return;
    int arow = row0 + m; if (arow > n - 1) arow = n - 1;
    f32x4 acc[8];
#pragma unroll
    for (int t = 0; t < 8; ++t) acc[t] = (f32x4){0.f, 0.f, 0.f, 0.f};
#pragma unroll
    for (int kc = 0; kc < 4; ++kc) {
        f16x8 a = *(const f16x8*)(h16 + (size_t)arow * 128 + kc * 32 + quad * 8);
#pragma unroll
        for (int t = 0; t < 8; ++t) {
            const __half* W = (t < 4) ? wp : wn;
            f16x8 bfr = *(const f16x8*)(W + (size_t)((t & 3) * 16 + m) * 128 + kc * 32 + quad * 8);
            acc[t] = __builtin_amdgcn_mfma_f32_16x16x32_f16(a, bfr, acc[t], 0, 0, 0);
        }
    }
    float sp[4], sn[4]; int rows[4];
#pragma unroll
    for (int r = 0; r < 4; ++r) {
        int rw = row0 + quad * 4 + r;
        rows[r] = rw;
        sp[r] = (rw < n) ? dinvp[rw] : 0.f;
        sn[r] = (rw < n) ? dinvn[rw] : 0.f;
    }
#pragma unroll
    for (int t = 0; t < 8; ++t) {
        int col = (t < 4 ? 0 : 64) + (t & 3) * 16 + m;
#pragma unroll
        for (int r = 0; r < 4; ++r)
            if (rows[r] < n) {
                float s = (t < 4) ? sp[r] : sn[r];
                g2[(size_t)rows[r] * 128 + col] = (__half)(acc[t][r] * s);
            }
    }
}

// ---------------------------------------------------------------------------
// Gather, layer 2 (F=64): reads the selected 128 B half-row of g2 per edge
// (offset = edat.x & ~127), nv signed. fp32 out to d_out.
// ---------------------------------------------------------------------------
__global__ __launch_bounds__(256) void gather64_kernel(
        const int* __restrict__ rowstart, const int2* __restrict__ edat,
        const __half* __restrict__ g2,
        const float* __restrict__ dinvp, const float* __restrict__ dinvn,
        const float* __restrict__ bp, const float* __restrict__ bn,
        float* __restrict__ out, int n) {
    const int lane = threadIdx.x & 63;
    int t = (blockIdx.x * blockDim.x + threadIdx.x) >> 6;
    if (t >= n) return;
    t = __builtin_amdgcn_readfirstlane(t);
    const char* gB = (const char*)g2;
    int beg = rowstart[t], end = rowstart[t + 1];
    float acc0 = 0.f, acc1 = 0.f, acc2 = 0.f, acc3 = 0.f;
    int e = beg;
    for (; e + 3 < end; e += 4) {
        int2 d0 = edat[e], d1 = edat[e + 1], d2 = edat[e + 2], d3 = edat[e + 3];
        const __half* r0 = (const __half*)(gB + (d0.x & 0xFFFFFF80u));
        const __half* r1 = (const __half*)(gB + (d1.x & 0xFFFFFF80u));
        const __half* r2 = (const __half*)(gB + (d2.x & 0xFFFFFF80u));
        const __half* r3 = (const __half*)(gB + (d3.x & 0xFFFFFF80u));
        acc0 += __half2float(r0[lane]) * __int_as_float(d0.y);
        acc1 += __half2float(r1[lane]) * __int_as_float(d1.y);
        acc2 += __half2float(r2[lane]) * __int_as_float(d2.y);
        acc3 += __half2float(r3[lane]) * __int_as_float(d3.y);
    }
    for (; e < end; ++e) {
        int2 d0 = edat[e];
        const __half* r0 = (const __half*)(gB + (d0.x & 0xFFFFFF80u));
        acc0 += __half2float(r0[lane]) * __int_as_float(d0.y);
    }
    const float dp = dinvp[t], dn = dinvn[t];
    float hpv = __half2float(g2[(size_t)t * 128 + lane]);
    float hnv = __half2float(g2[(size_t)t * 128 + 64 + lane]);
    float o = acc0 + acc1 + acc2 + acc3 + hpv * dp + bp[lane] - hnv * dn - bn[lane];
    out[(size_t)t * 64 + lane] = fmaxf(o, 0.f);
}

// ---------------------------------------------------------------------------
extern "C" void kernel_launch(void* const* d_in, const int* in_sizes, int n_in,
                              void* d_out, int out_size, void* d_ws, size_t ws_size,
                              hipStream_t stream) {
    const float* x   = (const float*)d_in[0];
    const int*   ei  = (const int*)d_in[1];
    const float* ew  = (const float*)d_in[2];
    const float* W1p = (const float*)d_in[3];
    const float* b1p = (const float*)d_in[4];
    const float* W1n = (const float*)d_in[5];
    const float* b1n = (const float*)d_in[6];
    const float* W2p = (const float*)d_in[7];
    const float* b2p = (const float*)d_in[8];
    const float* W2n = (const float*)d_in[9];
    const float* b2n = (const float*)d_in[10];

    const int E = in_sizes[2];
    const int n = in_sizes[0] / 64;  // IN = 64
    const int nb = (n + BTGT - 1) >> BSH;
    const int* src = ei;
    const int* tgt = ei + E;

    // ws layout (4B units): cnt_pad[4096] | cursor_pad[4096] | bucket_start[257]
    //   | (pad) dinvp[n] | dinvn[n] | rowstart[n+1] | (pad16) xs[128n]h |
    //   w16[32768]h | recs[E]int2 | edat[E]int2 | agg[128n]h | h[128n]h.
    //   g2 aliases agg (dead after gemm1).  ~104 MB.
    int* wsi          = (int*)d_ws;
    int* cnt_pad      = wsi;
    int* cursor_pad   = wsi + 4096;
    int* bucket_start = wsi + 8192;
    size_t o = 8452;                                  // 16B-aligned
    float* dinvp    = (float*)(wsi + o);  o += n;
    float* dinvn    = (float*)(wsi + o);  o += n;
    int*   rowstart = (int*)(wsi + o);    o += n + 1;
    o = (o + 3) & ~(size_t)3;
    __half* xs  = (__half*)(wsi + o);     o += (size_t)n * 64;   // 128n halves
    __half* w16 = (__half*)(wsi + o);     o += 16384;
    __half* w1p16 = w16, *w1n16 = w16 + 8192, *w2p16 = w16 + 16384, *w2n16 = w16 + 24576;
    int2* recs = (int2*)(wsi + o);        o += 2 * (size_t)E;
    int2* edat = (int2*)(wsi + o);        o += 2 * (size_t)E;
    __half* agg = (__half*)(wsi + o);     o += (size_t)n * 64;
    __half* h   = (__half*)(wsi + o);
    __half* g2  = agg;
    float*  out = (float*)d_out;

    hipMemsetAsync(cnt_pad, 0, 4096 * sizeof(int), stream);

    const int gridA  = (E + ACHUNK - 1) / ACHUNK;
    const int gridW  = (n * 64 + TPB - 1) / TPB;
    const int gridG  = (n + 63) / 64;     // 64 rows per block (4 waves x 16)
    const int gridCv = (n * 32 + 16384 + TPB - 1) / TPB;

    bucket_count_kernel<<<gridA, TPB, 0, stream>>>(tgt, cnt_pad, E);
    bucket_scan_kernel<<<1, TPB, 0, stream>>>(cnt_pad, bucket_start, cursor_pad, nb, E);
    bucket_scatter_kernel<<<gridA, TPB, 0, stream>>>(tgt, src, ew, cursor_pad, recs, E);
    csr_build_kernel<<<nb, TPB, 0, stream>>>(bucket_start, recs, rowstart, edat,
                                             dinvp, dinvn, n, nb, E);
    convert_kernel<<<gridCv, TPB, 0, stream>>>(x, dinvp, dinvn, W1p, W1n, W2p, W2n,
                                               xs, w16, n);

    // ---- layer 1: aggregate in x-space, then fused GEMM+bias+relu ----
    gatherX_kernel<<<gridW, TPB, 0, stream>>>(rowstart, edat, xs, dinvp, dinvn, agg, n);
    gemm1_mfma<<<gridG, TPB, 0, stream>>>(agg, w1p16, w1n16, b1p, b1n, h, n);

    // ---- layer 2: GEMM (combined g2), then gather ----
    gemm2_mfma<<<gridG, TPB, 0, stream>>>(h, w2p16, w2n16, dinvp, dinvn, g2, n);
    gather64_kernel<<<gridW, TPB, 0, stream>>>(rowstart, edat, g2, dinvp, dinvn,
                                               b2p, b2n, out, n);
}